// Round 3
// baseline (1019.740 us; speedup 1.0000x reference)
//
#include <hip/hip_runtime.h>
#include <cstdint>
#include <cstddef>

#define NN 32768
#define NE 524288
#define H  128
#define H3 384
#define RB 64
#define EB 16
#define NPB 4        // dst nodes per block in edge kernel
#define EEST 72      // padded LDS row stride (shorts) for ee tile
#define MSTRIDE 388  // padded LDS row stride (floats) for mst
#define AST 136      // padded LDS row stride (shorts) for 128-wide bf16 tiles

#define INV_SQRT_3 0.5773502691896258f
#define INV_SQRT_H 0.08838834764831845f
#define INV_SQRT_2 0.7071067811865476f

typedef __attribute__((ext_vector_type(8))) short short8;
typedef __attribute__((ext_vector_type(4))) float f32x4;

__device__ __forceinline__ float scaled_silu(float v) {
    return v * (1.0f / 0.6f) / (1.0f + __expf(-v));
}
__device__ __forceinline__ short f2bf(float f) {
    uint32_t u = __float_as_uint(f);
    uint32_t r = (u + 0x7FFFu + ((u >> 16) & 1u)) >> 16;
    return (short)r;
}
__device__ __forceinline__ float bf2f(short s) {
    return __uint_as_float(((uint32_t)(uint16_t)s) << 16);
}

// ---------------- weight transpose+bf16: WT[m][k] = bf16(W[k][m]) -----------
__global__ __launch_bounds__(256) void cvtT_kernel(const float* __restrict__ W,
        short* __restrict__ WT, int K, int M) {
    int i = blockIdx.x * 256 + threadIdx.x;  // i < K*M
    int k = i / M, m = i % M;
    WT[(size_t)m * K + k] = f2bf(W[(size_t)k * M + m]);
}

// ---------------- vec -> bf16 copy ------------------------------------------
__global__ __launch_bounds__(256) void veccvt_kernel(const float* __restrict__ v,
        short* __restrict__ vb) {
    int i = blockIdx.x * 256 + threadIdx.x;  // over N*H3/4
    float4 a = ((const float4*)v)[i];
    short4 s4; s4.x = f2bf(a.x); s4.y = f2bf(a.y); s4.z = f2bf(a.z); s4.w = f2bf(a.w);
    ((short4*)vb)[i] = s4;
}

// ---------------- LayerNorm: t = LN(x) --------------------------------------
__global__ __launch_bounds__(256) void ln_kernel(const float* __restrict__ x,
        const float* __restrict__ g, const float* __restrict__ b,
        float* __restrict__ t) {
    int row  = blockIdx.x * 4 + (threadIdx.x >> 6);
    int lane = threadIdx.x & 63;
    const float* xr = x + (size_t)row * H;
    float v0 = xr[lane], v1 = xr[lane + 64];
    float s = v0 + v1;
#pragma unroll
    for (int off = 32; off; off >>= 1) s += __shfl_xor(s, off, 64);
    float mu = s * (1.0f / 128.0f);
    float d0 = v0 - mu, d1 = v1 - mu;
    float q = d0 * d0 + d1 * d1;
#pragma unroll
    for (int off = 32; off; off >>= 1) q += __shfl_xor(q, off, 64);
    float rs = rsqrtf(q * (1.0f / 128.0f) + 1e-5f);
    float* tr = t + (size_t)row * H;
    tr[lane]      = d0 * rs * g[lane]      + b[lane];
    tr[lane + 64] = d1 * rs * g[lane + 64] + b[lane + 64];
}

// ---------------- G1: h1_bf = bf16(ssilu(t @ W1 + b1))  [N,128]x[128,128] ---
__global__ __launch_bounds__(256) void g1_mfma(const float* __restrict__ t,
        const short* __restrict__ W1T, const float* __restrict__ b1,
        short* __restrict__ h1_bf) {
    __shared__ short A_l[64 * AST];
    __shared__ short B_l[128 * AST];
    int tid = threadIdx.x;
    int w = tid >> 6, l = tid & 63, lm = l & 15, q = l >> 4;
    int r0 = blockIdx.x * 64;
    const float4* ag = (const float4*)(t + (size_t)r0 * H);
#pragma unroll
    for (int i = 0; i < 8; ++i) {
        int idx = tid + 256 * i;
        float4 a = ag[idx];
        int row = idx >> 5, c4 = idx & 31;
        short4 s4; s4.x = f2bf(a.x); s4.y = f2bf(a.y); s4.z = f2bf(a.z); s4.w = f2bf(a.w);
        *(short4*)&A_l[row * AST + c4 * 4] = s4;
    }
    const short8* wg = (const short8*)W1T;
#pragma unroll
    for (int i = 0; i < 8; ++i) {
        int idx = tid + 256 * i;
        int row = idx >> 4, c8 = idx & 15;
        *(short8*)&B_l[row * AST + c8 * 8] = wg[idx];
    }
    __syncthreads();
    short8 bf[2][4];
#pragma unroll
    for (int c = 0; c < 2; ++c)
#pragma unroll
        for (int ks = 0; ks < 4; ++ks)
            bf[c][ks] = *(const short8*)&B_l[((2 * w + c) * 16 + lm) * AST + ks * 32 + q * 8];
    f32x4 acc[4][2];
#pragma unroll
    for (int rt = 0; rt < 4; ++rt) { acc[rt][0] = (f32x4){0.f,0.f,0.f,0.f}; acc[rt][1] = (f32x4){0.f,0.f,0.f,0.f}; }
#pragma unroll
    for (int ks = 0; ks < 4; ++ks)
#pragma unroll
        for (int rt = 0; rt < 4; ++rt) {
            short8 a = *(const short8*)&A_l[(rt * 16 + lm) * AST + ks * 32 + q * 8];
            acc[rt][0] = __builtin_amdgcn_mfma_f32_16x16x32_bf16(a, bf[0][ks], acc[rt][0], 0, 0, 0);
            acc[rt][1] = __builtin_amdgcn_mfma_f32_16x16x32_bf16(a, bf[1][ks], acc[rt][1], 0, 0, 0);
        }
#pragma unroll
    for (int c = 0; c < 2; ++c) {
        int col = (2 * w + c) * 16 + lm;
        float bb = b1[col];
#pragma unroll
        for (int rt = 0; rt < 4; ++rt)
#pragma unroll
            for (int r = 0; r < 4; ++r) {
                int R = r0 + rt * 16 + q * 4 + r;
                h1_bf[(size_t)R * H + col] = f2bf(scaled_silu(acc[rt][c][r] + bb));
            }
    }
}

// ---------------- G2: xh_bf = bf16(h1 @ W2 + b2)  [N,128]x[128,384] ---------
__global__ __launch_bounds__(256) void g2_mfma(const short* __restrict__ h1_bf,
        const short* __restrict__ W2T, const float* __restrict__ b2,
        short* __restrict__ xh_bf) {
    __shared__ short A_l[64 * AST];
    __shared__ short B_l[128 * AST];
    int tid = threadIdx.x;
    int w = tid >> 6, l = tid & 63, lm = l & 15, q = l >> 4;
    int r0 = blockIdx.x * 64;
    const short8* ag = (const short8*)(h1_bf + (size_t)r0 * H);
#pragma unroll
    for (int i = 0; i < 4; ++i) {
        int idx = tid + 256 * i;
        int row = idx >> 4, c8 = idx & 15;
        *(short8*)&A_l[row * AST + c8 * 8] = ag[idx];
    }
    for (int s = 0; s < 3; ++s) {
        __syncthreads();
        const short8* wg = (const short8*)(W2T + (size_t)s * 128 * 128);
#pragma unroll
        for (int i = 0; i < 8; ++i) {
            int idx = tid + 256 * i;
            int row = idx >> 4, c8 = idx & 15;
            *(short8*)&B_l[row * AST + c8 * 8] = wg[idx];
        }
        __syncthreads();
        short8 bf[2][4];
#pragma unroll
        for (int c = 0; c < 2; ++c)
#pragma unroll
            for (int ks = 0; ks < 4; ++ks)
                bf[c][ks] = *(const short8*)&B_l[((2 * w + c) * 16 + lm) * AST + ks * 32 + q * 8];
        f32x4 acc[4][2];
#pragma unroll
        for (int rt = 0; rt < 4; ++rt) { acc[rt][0] = (f32x4){0.f,0.f,0.f,0.f}; acc[rt][1] = (f32x4){0.f,0.f,0.f,0.f}; }
#pragma unroll
        for (int ks = 0; ks < 4; ++ks)
#pragma unroll
            for (int rt = 0; rt < 4; ++rt) {
                short8 a = *(const short8*)&A_l[(rt * 16 + lm) * AST + ks * 32 + q * 8];
                acc[rt][0] = __builtin_amdgcn_mfma_f32_16x16x32_bf16(a, bf[0][ks], acc[rt][0], 0, 0, 0);
                acc[rt][1] = __builtin_amdgcn_mfma_f32_16x16x32_bf16(a, bf[1][ks], acc[rt][1], 0, 0, 0);
            }
#pragma unroll
        for (int c = 0; c < 2; ++c) {
            int col = (2 * w + c) * 16 + lm;
            float bb = b2[s * H + col];
#pragma unroll
            for (int rt = 0; rt < 4; ++rt)
#pragma unroll
                for (int r = 0; r < 4; ++r) {
                    int R = r0 + rt * 16 + q * 4 + r;
                    xh_bf[(size_t)R * H3 + s * H + col] = f2bf(acc[rt][c][r] + bb);
                }
        }
    }
}

// ---------------- Sort pass 1: histogram of dst -----------------------------
__global__ __launch_bounds__(256) void hist_kernel(const int* __restrict__ eidx,
        int* __restrict__ hist) {
    int e = blockIdx.x * 256 + threadIdx.x;
    atomicAdd(&hist[eidx[NE + e]], 1);
}

// ---------------- Sort pass 2: exclusive scan of 32768 counts ---------------
__global__ __launch_bounds__(1024) void scan_kernel(const int* __restrict__ hist,
        int* __restrict__ row_ptr, int* __restrict__ cursor) {
    __shared__ int sc[1024];
    int t = threadIdx.x;
    int base = t * 32;
    int v[32];
    int s = 0;
#pragma unroll
    for (int i = 0; i < 32; ++i) {
        int tmp = hist[base + i];
        v[i] = s;
        s += tmp;
    }
    sc[t] = s;
    __syncthreads();
    for (int off = 1; off < 1024; off <<= 1) {
        int a = sc[t];
        int b = (t >= off) ? sc[t - off] : 0;
        __syncthreads();
        sc[t] = a + b;
        __syncthreads();
    }
    int excl = sc[t] - s;
#pragma unroll
    for (int i = 0; i < 32; ++i) {
        int val = excl + v[i];
        row_ptr[base + i] = val;
        cursor[base + i] = val;
    }
    if (t == 0) row_ptr[32768] = NE;
}

// ---------------- Sort pass 3: scatter edges into dst-sorted order ----------
__global__ __launch_bounds__(256) void scatter_kernel(const int* __restrict__ eidx,
        const float* __restrict__ evec, int* __restrict__ cursor,
        int* __restrict__ perm, int* __restrict__ srcs_s, int* __restrict__ dsts_s,
        float* __restrict__ ev_s) {
    int e = blockIdx.x * 256 + threadIdx.x;
    int d = eidx[NE + e];
    int pos = atomicAdd(&cursor[d], 1);
    perm[pos]   = e;
    srcs_s[pos] = eidx[e];
    dsts_s[pos] = d;
    ev_s[pos * 3 + 0] = evec[e * 3 + 0];
    ev_s[pos * 3 + 1] = evec[e * 3 + 1];
    ev_s[pos * 3 + 2] = evec[e * 3 + 2];
}

// ---------------- Wr^T bf16 precompute --------------------------------------
__global__ __launch_bounds__(256) void wrt_kernel(const float* __restrict__ Wr,
        short* __restrict__ WrT16) {
    int i = blockIdx.x * 256 + threadIdx.x;  // over 384*64
    int n = i >> 6, k = i & 63;
    WrT16[i] = f2bf(Wr[(size_t)k * H3 + n]);
}

// ---------------- Edge kernel (CSR + MFMA, bf16 gathers) --------------------
// Round-2 body + two changes:
//  (a) staging pipeline: chunk k+1's perm/meta loads are issued FIRST in
//      chunk k's compute phase (vmcnt FIFO -> the dependent eembed gather
//      waits only on perm, not xg/vv); eembed gather lands in registers and
//      is written to LDS after the accumulate barrier. Staging latency hides
//      under compute for 3 of ~4 chunks per block.
//  (b) d1a folded into the writeout: dx_out <- x_mid, dvec_out <- vec_mid.
__global__ __launch_bounds__(384) void edge_mfma_kernel(
        const int* __restrict__ row_ptr, const int* __restrict__ perm,
        const int* __restrict__ srcs_s, const int* __restrict__ dsts_s,
        const float* __restrict__ ev_s, const float* __restrict__ eembed,
        const short* __restrict__ WrT16, const float* __restrict__ br,
        const short* __restrict__ xh_bf, const short* __restrict__ vec_bf,
        const float* __restrict__ xin, const float* __restrict__ vecin,
        float* __restrict__ dx_out, float* __restrict__ dvec_out) {
    __shared__ float accdx[NPB * H];
    __shared__ float accdv[NPB * H3];
    __shared__ short eeL[EB * EEST];
    __shared__ float mst[EB * MSTRIDE];
    __shared__ int   sSrc[EB];
    __shared__ int   sLd[EB];
    __shared__ float sEv[EB][3];
    int j = threadIdx.x;
    int w = j >> 6, l = j & 63;
    int lm = l & 15, q = l >> 4;
    short8 bfrag[4][2];
#pragma unroll
    for (int t = 0; t < 4; ++t)
#pragma unroll
        for (int hf = 0; hf < 2; ++hf)
            bfrag[t][hf] = *(const short8*)(WrT16 +
                ((size_t)(w * 64 + t * 16 + lm) * 64 + q * 8 + hf * 32));
    float brj[4];
#pragma unroll
    for (int t = 0; t < 4; ++t) brj[t] = br[w * 64 + t * 16 + lm];
    float scale = (w < 2) ? 1.0f : ((w < 4) ? (INV_SQRT_3 * INV_SQRT_H) : INV_SQRT_H);
    int n0 = blockIdx.x * NPB;
    for (int i = j; i < NPB * H;  i += 384) accdx[i] = 0.f;
    for (int i = j; i < NPB * H3; i += 384) accdv[i] = 0.f;
    int ib = row_ptr[n0], ie = row_ptr[n0 + NPB];
    int c = j >> 7, hh = j & 127;

    // prologue: stage chunk 0 directly to LDS
    if (ib < ie) {
        int cnt0 = min(EB, ie - ib);
        if (j < 256) {
            int e = j >> 4, c4 = j & 15;
            int i = ib + ((e < cnt0) ? e : 0);
            int p = perm[i];
            float4 a = ((const float4*)(eembed + (size_t)p * RB))[c4];
            short4 b4;
            b4.x = f2bf(a.x); b4.y = f2bf(a.y); b4.z = f2bf(a.z); b4.w = f2bf(a.w);
            *(short4*)(eeL + e * EEST + c4 * 4) = b4;
        }
        if (j < EB) {
            int i = ib + ((j < cnt0) ? j : 0);
            sSrc[j] = srcs_s[i];
            sLd[j]  = dsts_s[i] - n0;
            sEv[j][0] = ev_s[(size_t)i * 3 + 0];
            sEv[j][1] = ev_s[(size_t)i * 3 + 1];
            sEv[j][2] = ev_s[(size_t)i * 3 + 2];
        }
    }

    for (int base = ib; base < ie; base += EB) {
        int cnt = min(EB, ie - base);
        __syncthreads();   // eeL + meta (and zeroed accs on iter 0) visible
        // ---- issue next chunk's perm + meta FIRST (oldest in vmcnt FIFO) ---
        int nbase = base + EB;
        int hn = nbase < ie;
        int np = 0, msrc = 0, mdst = 0;
        float me0 = 0.f, me1 = 0.f, me2 = 0.f;
        if (hn) {
            int cntn = min(EB, ie - nbase);
            if (j < 256) {
                int e = j >> 4;
                np = perm[nbase + ((e < cntn) ? e : 0)];
            }
            if (j < EB) {
                int i = nbase + ((j < cntn) ? j : 0);
                msrc = srcs_s[i]; mdst = dsts_s[i];
                me0 = ev_s[(size_t)i * 3 + 0];
                me1 = ev_s[(size_t)i * 3 + 1];
                me2 = ev_s[(size_t)i * 3 + 2];
            }
        }
        // ---- xg gathers (drained by the mst write's vmcnt) ----
        short xg[4][4];
#pragma unroll
        for (int r = 0; r < 4; ++r) {
            const short* xr = xh_bf + (size_t)sSrc[q * 4 + r] * H3 + w * 64 + lm;
#pragma unroll
            for (int t = 0; t < 4; ++t) xg[r][t] = xr[t * 16];
        }
        // ---- vv gathers: stay in flight across MFMA+mst+barrier ----
        short vv[EB];
#pragma unroll
        for (int e = 0; e < EB; ++e)
            vv[e] = vec_bf[(size_t)sSrc[e] * H3 + j];
        // ---- MFMA: rbfh tile ----
        short8 a0 = *(const short8*)(eeL + lm * EEST + q * 8);
        short8 a1 = *(const short8*)(eeL + lm * EEST + 32 + q * 8);
        f32x4 d[4];
#pragma unroll
        for (int t = 0; t < 4; ++t) {
            d[t] = __builtin_amdgcn_mfma_f32_16x16x32_bf16(a0, bfrag[t][0],
                       (f32x4){0.f, 0.f, 0.f, 0.f}, 0, 0, 0);
            d[t] = __builtin_amdgcn_mfma_f32_16x16x32_bf16(a1, bfrag[t][1], d[t], 0, 0, 0);
        }
        // ---- issue next chunk's eembed gather (waits only on perm) ----
        float4 ereg;
        if (hn && j < 256) {
            int c4 = j & 15;
            ereg = ((const float4*)(eembed + (size_t)np * RB))[c4];
        }
        // ---- m = (rbfh + br) * xh[src] * scale -> LDS ----
#pragma unroll
        for (int r = 0; r < 4; ++r) {
            int e = q * 4 + r;
#pragma unroll
            for (int t = 0; t < 4; ++t) {
                float m = (d[t][r] + brj[t]) * bf2f(xg[r][t]) * scale;
                mst[e * MSTRIDE + w * 64 + t * 16 + lm] = m;
            }
        }
        __syncthreads();
        // ---- segmented accumulate (vv already in registers) ----
        int cur = -1; float dva = 0.f, dxa = 0.f;
#pragma unroll
        for (int e = 0; e < EB; ++e) {
            if (e < cnt) {
                float m2 = mst[e * MSTRIDE + H + hh];
                float m3 = mst[e * MSTRIDE + 2 * H + hh];
                int ld = sLd[e];
                if (ld != cur) {
                    if (cur >= 0) {
                        accdv[cur * H3 + j] += dva;
                        if (j < H) accdx[cur * H + j] += dxa;
                    }
                    cur = ld; dva = 0.f; dxa = 0.f;
                }
                dva += bf2f(vv[e]) * m2 + m3 * sEv[e][c];
                if (j < H) dxa += mst[e * MSTRIDE + j];
            }
        }
        if (cur >= 0) {
            accdv[cur * H3 + j] += dva;
            if (j < H) accdx[cur * H + j] += dxa;
        }
        __syncthreads();   // mst + eeL consumed; safe to overwrite staging
        // ---- write next chunk's staging to LDS (visible at loop-top bar) ---
        if (hn) {
            if (j < 256) {
                int e = j >> 4, c4 = j & 15;
                short4 b4;
                b4.x = f2bf(ereg.x); b4.y = f2bf(ereg.y);
                b4.z = f2bf(ereg.z); b4.w = f2bf(ereg.w);
                *(short4*)(eeL + e * EEST + c4 * 4) = b4;
            }
            if (j < EB) {
                sSrc[j] = msrc; sLd[j] = mdst - n0;
                sEv[j][0] = me0; sEv[j][1] = me1; sEv[j][2] = me2;
            }
        }
    }
    // writeout with d1a folded in: x_mid = (x+dx)*c ; vec_mid = vec+dvec
    for (int i = j; i < NPB * H;  i += 384)
        dx_out[(size_t)n0 * H + i] = (xin[(size_t)n0 * H + i] + accdx[i]) * INV_SQRT_2;
    for (int i = j; i < NPB * H3; i += 384)
        dvec_out[(size_t)n0 * H3 + i] = vecin[(size_t)n0 * H3 + i] + accdv[i];
}

// ---------------- D1: vproj MFMA + dot/norm fused (48 rows = 16 nodes) ------
__global__ __launch_bounds__(256) void d1_vproj(const float* __restrict__ vec_mid,
        const short* __restrict__ WvT, float* __restrict__ vec1,
        float* __restrict__ vdot, short* __restrict__ vnorm_bf) {
    __shared__ short A_l[48 * AST];
    __shared__ short B_l[128 * AST];
    __shared__ float T1[48 * 132];
    __shared__ float T2[48 * 132];
    int tid = threadIdx.x;
    int w = tid >> 6, l = tid & 63, lm = l & 15, q = l >> 4;
    int r0 = blockIdx.x * 48;
    const float4* ag = (const float4*)(vec_mid + (size_t)r0 * H);
#pragma unroll
    for (int i = 0; i < 6; ++i) {
        int idx = tid + 256 * i;
        float4 a = ag[idx];
        int row = idx >> 5, c4 = idx & 31;
        short4 s4; s4.x = f2bf(a.x); s4.y = f2bf(a.y); s4.z = f2bf(a.z); s4.w = f2bf(a.w);
        *(short4*)&A_l[row * AST + c4 * 4] = s4;
    }
    for (int s = 0; s < 2; ++s) {
        __syncthreads();
        const short8* wg = (const short8*)(WvT + (size_t)s * 128 * 128);
#pragma unroll
        for (int i = 0; i < 8; ++i) {
            int idx = tid + 256 * i;
            int row = idx >> 4, c8 = idx & 15;
            *(short8*)&B_l[row * AST + c8 * 8] = wg[idx];
        }
        __syncthreads();
        short8 bf[2][4];
#pragma unroll
        for (int c = 0; c < 2; ++c)
#pragma unroll
            for (int ks = 0; ks < 4; ++ks)
                bf[c][ks] = *(const short8*)&B_l[((2 * w + c) * 16 + lm) * AST + ks * 32 + q * 8];
        f32x4 acc[3][2];
#pragma unroll
        for (int rt = 0; rt < 3; ++rt) { acc[rt][0] = (f32x4){0.f,0.f,0.f,0.f}; acc[rt][1] = (f32x4){0.f,0.f,0.f,0.f}; }
#pragma unroll
        for (int ks = 0; ks < 4; ++ks)
#pragma unroll
            for (int rt = 0; rt < 3; ++rt) {
                short8 a = *(const short8*)&A_l[(rt * 16 + lm) * AST + ks * 32 + q * 8];
                acc[rt][0] = __builtin_amdgcn_mfma_f32_16x16x32_bf16(a, bf[0][ks], acc[rt][0], 0, 0, 0);
                acc[rt][1] = __builtin_amdgcn_mfma_f32_16x16x32_bf16(a, bf[1][ks], acc[rt][1], 0, 0, 0);
            }
        float* T = s ? T2 : T1;
#pragma unroll
        for (int c = 0; c < 2; ++c) {
            int col = (2 * w + c) * 16 + lm;
#pragma unroll
            for (int rt = 0; rt < 3; ++rt)
#pragma unroll
                for (int r = 0; r < 4; ++r) {
                    int lr = rt * 16 + q * 4 + r;
                    float v = acc[rt][c][r];
                    T[lr * 132 + col] = v;
                    if (s == 0) vec1[(size_t)(r0 + lr) * H + col] = v;
                }
        }
    }
    __syncthreads();
    int nb = blockIdx.x * 16;
#pragma unroll
    for (int i = 0; i < 8; ++i) {
        int p = tid + 256 * i;  // 2048 (node, col) pairs
        int k = p & 127, m = p >> 7;
        float d = 0.f, s2 = 0.f;
#pragma unroll
        for (int c = 0; c < 3; ++c) {
            float v1 = T1[(m * 3 + c) * 132 + k];
            float v2 = T2[(m * 3 + c) * 132 + k];
            d += v1 * v2; s2 += v2 * v2;
        }
        vdot[(size_t)(nb + m) * H + k] = d * INV_SQRT_H;
        vnorm_bf[(size_t)(nb + m) * H + k] = f2bf(sqrtf(s2 + 1e-8f));
    }
}

// ---------------- D2a: u_bf = bf16(ssilu([x_mid, vnorm] @ Wu1 + bu1)) -------
__global__ __launch_bounds__(256) void d2a_mfma(const float* __restrict__ xmid,
        const short* __restrict__ vnorm_bf, const short* __restrict__ Wu1T,
        const float* __restrict__ bu1, short* __restrict__ u_bf) {
    __shared__ short A_l[64 * AST];
    __shared__ short B_l[128 * AST];
    int tid = threadIdx.x;
    int w = tid >> 6, l = tid & 63, lm = l & 15, q = l >> 4;
    int r0 = blockIdx.x * 64;
    f32x4 acc[4][2];
#pragma unroll
    for (int rt = 0; rt < 4; ++rt) { acc[rt][0] = (f32x4){0.f,0.f,0.f,0.f}; acc[rt][1] = (f32x4){0.f,0.f,0.f,0.f}; }
    for (int kh = 0; kh < 2; ++kh) {
        __syncthreads();
        if (kh == 0) {
            const float4* ag = (const float4*)(xmid + (size_t)r0 * H);
#pragma unroll
            for (int i = 0; i < 8; ++i) {
                int idx = tid + 256 * i;
                float4 a = ag[idx];
                int row = idx >> 5, c4 = idx & 31;
                short4 s4; s4.x = f2bf(a.x); s4.y = f2bf(a.y); s4.z = f2bf(a.z); s4.w = f2bf(a.w);
                *(short4*)&A_l[row * AST + c4 * 4] = s4;
            }
        } else {
            const short8* ag = (const short8*)(vnorm_bf + (size_t)r0 * H);
#pragma unroll
            for (int i = 0; i < 4; ++i) {
                int idx = tid + 256 * i;
                int row = idx >> 4, c8 = idx & 15;
                *(short8*)&A_l[row * AST + c8 * 8] = ag[idx];
            }
        }
#pragma unroll
        for (int i = 0; i < 8; ++i) {
            int idx = tid + 256 * i;
            int row = idx >> 4, c8 = idx & 15;
            *(short8*)&B_l[row * AST + c8 * 8] = ((const short8*)Wu1T)[row * 32 + kh * 16 + c8];
        }
        __syncthreads();
        short8 bf[2][4];
#pragma unroll
        for (int c = 0; c < 2; ++c)
#pragma unroll
            for (int ks = 0; ks < 4; ++ks)
                bf[c][ks] = *(const short8*)&B_l[((2 * w + c) * 16 + lm) * AST + ks * 32 + q * 8];
#pragma unroll
        for (int ks = 0; ks < 4; ++ks)
#pragma unroll
            for (int rt = 0; rt < 4; ++rt) {
                short8 a = *(const short8*)&A_l[(rt * 16 + lm) * AST + ks * 32 + q * 8];
                acc[rt][0] = __builtin_amdgcn_mfma_f32_16x16x32_bf16(a, bf[0][ks], acc[rt][0], 0, 0, 0);
                acc[rt][1] = __builtin_amdgcn_mfma_f32_16x16x32_bf16(a, bf[1][ks], acc[rt][1], 0, 0, 0);
            }
    }
#pragma unroll
    for (int c = 0; c < 2; ++c) {
        int col = (2 * w + c) * 16 + lm;
        float bb = bu1[col];
#pragma unroll
        for (int rt = 0; rt < 4; ++rt)
#pragma unroll
            for (int r = 0; r < 4; ++r) {
                int R = r0 + rt * 16 + q * 4 + r;
                u_bf[(size_t)R * H + col] = f2bf(scaled_silu(acc[rt][c][r] + bb));
            }
    }
}

// ---------------- D2b: h = u @ Wu2 + bu2; final outputs ---------------------
__global__ __launch_bounds__(256) void d2b_mfma(const short* __restrict__ u_bf,
        const short* __restrict__ Wu2T, const float* __restrict__ bu2,
        const float* __restrict__ vdot, const float* __restrict__ xmid,
        const float* __restrict__ vec_mid, const float* __restrict__ vec1,
        float* __restrict__ out) {
    __shared__ short A_l[64 * AST];
    __shared__ short B_l[128 * AST];
    int tid = threadIdx.x;
    int w = tid >> 6, l = tid & 63, lm = l & 15, q = l >> 4;
    int r0 = blockIdx.x * 64;
    float* out_vec = out;
    float* out_x = out + (size_t)NN * H3;
    const short8* ag = (const short8*)(u_bf + (size_t)r0 * H);
#pragma unroll
    for (int i = 0; i < 4; ++i) {
        int idx = tid + 256 * i;
        int row = idx >> 4, c8 = idx & 15;
        *(short8*)&A_l[row * AST + c8 * 8] = ag[idx];
    }
    // stage slice 0, keep frags; stage slice 1, keep frags; dual K-loop
    short8 bf0[2][4], bf1[2][4];
    __syncthreads();
    {
        const short8* wg = (const short8*)Wu2T;
#pragma unroll
        for (int i = 0; i < 8; ++i) {
            int idx = tid + 256 * i;
            int row = idx >> 4, c8 = idx & 15;
            *(short8*)&B_l[row * AST + c8 * 8] = wg[idx];
        }
    }
    __syncthreads();
#pragma unroll
    for (int c = 0; c < 2; ++c)
#pragma unroll
        for (int ks = 0; ks < 4; ++ks)
            bf0[c][ks] = *(const short8*)&B_l[((2 * w + c) * 16 + lm) * AST + ks * 32 + q * 8];
    __syncthreads();
    {
        const short8* wg = (const short8*)(Wu2T + 128 * 128);
#pragma unroll
        for (int i = 0; i < 8; ++i) {
            int idx = tid + 256 * i;
            int row = idx >> 4, c8 = idx & 15;
            *(short8*)&B_l[row * AST + c8 * 8] = wg[idx];
        }
    }
    __syncthreads();
#pragma unroll
    for (int c = 0; c < 2; ++c)
#pragma unroll
        for (int ks = 0; ks < 4; ++ks)
            bf1[c][ks] = *(const short8*)&B_l[((2 * w + c) * 16 + lm) * AST + ks * 32 + q * 8];
    f32x4 acc0[4][2], acc1[4][2];
#pragma unroll
    for (int rt = 0; rt < 4; ++rt) {
        acc0[rt][0] = (f32x4){0.f,0.f,0.f,0.f}; acc0[rt][1] = (f32x4){0.f,0.f,0.f,0.f};
        acc1[rt][0] = (f32x4){0.f,0.f,0.f,0.f}; acc1[rt][1] = (f32x4){0.f,0.f,0.f,0.f};
    }
#pragma unroll
    for (int ks = 0; ks < 4; ++ks)
#pragma unroll
        for (int rt = 0; rt < 4; ++rt) {
            short8 a = *(const short8*)&A_l[(rt * 16 + lm) * AST + ks * 32 + q * 8];
            acc0[rt][0] = __builtin_amdgcn_mfma_f32_16x16x32_bf16(a, bf0[0][ks], acc0[rt][0], 0, 0, 0);
            acc0[rt][1] = __builtin_amdgcn_mfma_f32_16x16x32_bf16(a, bf0[1][ks], acc0[rt][1], 0, 0, 0);
            acc1[rt][0] = __builtin_amdgcn_mfma_f32_16x16x32_bf16(a, bf1[0][ks], acc1[rt][0], 0, 0, 0);
            acc1[rt][1] = __builtin_amdgcn_mfma_f32_16x16x32_bf16(a, bf1[1][ks], acc1[rt][1], 0, 0, 0);
        }
    // epilogue: out_x = x_mid + (xv1 + xv2*vdot)*INV_SQRT_2
#pragma unroll
    for (int c = 0; c < 2; ++c) {
        int col = (2 * w + c) * 16 + lm;
        float bb0 = bu2[col], bb1 = bu2[H + col];
#pragma unroll
        for (int rt = 0; rt < 4; ++rt)
#pragma unroll
            for (int r = 0; r < 4; ++r) {
                int R = r0 + rt * 16 + q * 4 + r;
                float xv1 = acc0[rt][c][r] + bb0;
                float xv2 = acc1[rt][c][r] + bb1;
                float dx2 = (xv1 + xv2 * vdot[(size_t)R * H + col]) * INV_SQRT_2;
                out_x[(size_t)R * H + col] = xmid[(size_t)R * H + col] + dx2;
            }
    }
    // slice 2 (xv3) -> out_vec
    __syncthreads();
    {
        const short8* wg = (const short8*)(Wu2T + 2 * 128 * 128);
#pragma unroll
        for (int i = 0; i < 8; ++i) {
            int idx = tid + 256 * i;
            int row = idx >> 4, c8 = idx & 15;
            *(short8*)&B_l[row * AST + c8 * 8] = wg[idx];
        }
    }
    __syncthreads();
#pragma unroll
    for (int c = 0; c < 2; ++c)
#pragma unroll
        for (int ks = 0; ks < 4; ++ks)
            bf0[c][ks] = *(const short8*)&B_l[((2 * w + c) * 16 + lm) * AST + ks * 32 + q * 8];
#pragma unroll
    for (int rt = 0; rt < 4; ++rt) { acc0[rt][0] = (f32x4){0.f,0.f,0.f,0.f}; acc0[rt][1] = (f32x4){0.f,0.f,0.f,0.f}; }
#pragma unroll
    for (int ks = 0; ks < 4; ++ks)
#pragma unroll
        for (int rt = 0; rt < 4; ++rt) {
            short8 a = *(const short8*)&A_l[(rt * 16 + lm) * AST + ks * 32 + q * 8];
            acc0[rt][0] = __builtin_amdgcn_mfma_f32_16x16x32_bf16(a, bf0[0][ks], acc0[rt][0], 0, 0, 0);
            acc0[rt][1] = __builtin_amdgcn_mfma_f32_16x16x32_bf16(a, bf0[1][ks], acc0[rt][1], 0, 0, 0);
        }
#pragma unroll
    for (int c = 0; c < 2; ++c) {
        int col = (2 * w + c) * 16 + lm;
        float bb2 = bu2[2 * H + col];
#pragma unroll
        for (int rt = 0; rt < 4; ++rt)
#pragma unroll
            for (int r = 0; r < 4; ++r) {
                int R = r0 + rt * 16 + q * 4 + r;
                float xv3 = acc0[rt][c][r] + bb2;
#pragma unroll
                for (int c3 = 0; c3 < 3; ++c3) {
                    size_t idx = (size_t)R * H3 + c3 * H + col;
                    out_vec[idx] = vec_mid[idx] + xv3 * vec1[idx];
                }
            }
    }
}

extern "C" void kernel_launch(void* const* d_in, const int* in_sizes, int n_in,
                              void* d_out, int out_size, void* d_ws, size_t ws_size,
                              hipStream_t stream) {
    const float* x    = (const float*)d_in[0];
    const float* vec  = (const float*)d_in[1];
    const int*   eidx = (const int*)d_in[2];
    const float* eemb = (const float*)d_in[3];
    const float* evec = (const float*)d_in[4];
    const float* lng  = (const float*)d_in[5];
    const float* lnb  = (const float*)d_in[6];
    const float* W1   = (const float*)d_in[7];
    const float* b1   = (const float*)d_in[8];
    const float* W2   = (const float*)d_in[9];
    const float* b2   = (const float*)d_in[10];
    const float* Wr   = (const float*)d_in[11];
    const float* br   = (const float*)d_in[12];
    const float* Wv   = (const float*)d_in[13];
    const float* Wu1  = (const float*)d_in[14];
    const float* bu1  = (const float*)d_in[15];
    const float* Wu2  = (const float*)d_in[16];
    const float* bu2  = (const float*)d_in[17];

    // workspace layout:
    // B0: N*384 f32 : xh_bf16 (as shorts) -> vec1 f32
    // B1: N*384 f32 : dvec/vec_mid (edge kernel writes vec_mid directly)
    // B2: N*128 f32 : t(LN) -> x_mid (edge kernel writes x_mid directly)
    // B3: N*128 f32 : h1_bf16 (as shorts) -> vec_dot f32
    // B4: N*128 f32 : [sort scratch + WrT16] -> vnorm_bf16 + u_bf16
    // B5: vec_bf16 (N*384 shorts) + bf16 transposed weights
    float* B0 = (float*)d_ws;
    float* B1 = B0 + (size_t)NN * H3;
    float* B2 = B1 + (size_t)NN * H3;
    float* B3 = B2 + (size_t)NN * H;
    float* B4 = B3 + (size_t)NN * H;
    short* B5 = (short*)(B4 + (size_t)NN * H);
    float* out = (float*)d_out;

    int* row_ptr = (int*)B4;
    int* cursor  = row_ptr + 32772;
    int* perm    = cursor + 32768;
    int* srcs_s  = perm + NE;
    int* dsts_s  = srcs_s + NE;
    float* ev_s  = (float*)(dsts_s + NE);
    short* WrT16 = (short*)(ev_s + (size_t)NE * 3);

    short* vec_bf = B5;
    short* W1T  = vec_bf + (size_t)NN * H3;
    short* W2T  = W1T + 128 * 128;
    short* WvT  = W2T + 128 * 384;
    short* Wu1T = WvT + 128 * 256;
    short* Wu2T = Wu1T + 256 * 128;

    short* xh_bf    = (short*)B0;
    short* h1_bf    = (short*)B3;
    short* vnorm_bf = (short*)B4;
    short* u_bf     = vnorm_bf + (size_t)NN * H;

    // weight conversions + vec bf16 copy
    cvtT_kernel<<<64,  256, 0, stream>>>(W1,  W1T,  128, 128);
    cvtT_kernel<<<192, 256, 0, stream>>>(W2,  W2T,  128, 384);
    cvtT_kernel<<<128, 256, 0, stream>>>(Wv,  WvT,  128, 256);
    cvtT_kernel<<<128, 256, 0, stream>>>(Wu1, Wu1T, 256, 128);
    cvtT_kernel<<<192, 256, 0, stream>>>(Wu2, Wu2T, 128, 384);
    wrt_kernel<<<(H3 * RB) / 256, 256, 0, stream>>>(Wr, WrT16);
    veccvt_kernel<<<(NN * H3 / 4) / 256, 256, 0, stream>>>(vec, vec_bf);

    // node message path
    ln_kernel<<<NN / 4, 256, 0, stream>>>(x, lng, lnb, B2);
    g1_mfma<<<NN / 64, 256, 0, stream>>>(B2, W1T, b1, h1_bf);
    g2_mfma<<<NN / 64, 256, 0, stream>>>(h1_bf, W2T, b2, xh_bf);

    // dst counting sort -> CSR
    hipMemsetAsync(row_ptr, 0, 32768 * sizeof(int), stream);
    hist_kernel<<<NE / 256, 256, 0, stream>>>(eidx, row_ptr);
    scan_kernel<<<1, 1024, 0, stream>>>(row_ptr, row_ptr, cursor);
    scatter_kernel<<<NE / 256, 256, 0, stream>>>(eidx, evec, cursor, perm, srcs_s, dsts_s, ev_s);

    // fused edge message + segment reduce + d1a fold
    // (x_mid -> B2, vec_mid -> B1)
    edge_mfma_kernel<<<NN / NPB, 384, 0, stream>>>(row_ptr, perm, srcs_s, dsts_s, ev_s,
                                                   eemb, WrT16, br, xh_bf, vec_bf,
                                                   x, vec, B2, B1);

    // update path
    d1_vproj<<<(NN * 3) / 48, 256, 0, stream>>>(B1, WvT, B0, B3, vnorm_bf);
    d2a_mfma<<<NN / 64, 256, 0, stream>>>(B2, vnorm_bf, Wu1T, bu1, u_bf);
    d2b_mfma<<<NN / 64, 256, 0, stream>>>(u_bf, Wu2T, bu2, B3, B2, B1, B0, out);
}

// Round 4
// 937.043 us; speedup vs baseline: 1.0883x; 1.0883x over previous
//
#include <hip/hip_runtime.h>
#include <cstdint>
#include <cstddef>

#define NN 32768
#define NE 524288
#define H  128
#define H3 384
#define RB 64
#define EB 16
#define NPB 4        // dst nodes per block in edge kernel
#define EEST 72      // padded LDS row stride (shorts) for ee tile
#define MSTRIDE 388  // padded LDS row stride (floats) for mst
#define AST 136      // padded LDS row stride (shorts) for 128-wide bf16 tiles

#define INV_SQRT_3 0.5773502691896258f
#define INV_SQRT_H 0.08838834764831845f
#define INV_SQRT_2 0.7071067811865476f

typedef __attribute__((ext_vector_type(8))) short short8;
typedef __attribute__((ext_vector_type(4))) float f32x4;

__device__ __forceinline__ float scaled_silu(float v) {
    return v * (1.0f / 0.6f) / (1.0f + __expf(-v));
}
__device__ __forceinline__ short f2bf(float f) {
    uint32_t u = __float_as_uint(f);
    uint32_t r = (u + 0x7FFFu + ((u >> 16) & 1u)) >> 16;
    return (short)r;
}
__device__ __forceinline__ float bf2f(short s) {
    return __uint_as_float(((uint32_t)(uint16_t)s) << 16);
}

// ---------------- weight transpose+bf16: WT[m][k] = bf16(W[k][m]) -----------
__global__ __launch_bounds__(256) void cvtT_kernel(const float* __restrict__ W,
        short* __restrict__ WT, int K, int M) {
    int i = blockIdx.x * 256 + threadIdx.x;  // i < K*M
    int k = i / M, m = i % M;
    WT[(size_t)m * K + k] = f2bf(W[(size_t)k * M + m]);
}

// ---------------- vec -> bf16 copy ------------------------------------------
__global__ __launch_bounds__(256) void veccvt_kernel(const float* __restrict__ v,
        short* __restrict__ vb) {
    int i = blockIdx.x * 256 + threadIdx.x;  // over N*H3/4
    float4 a = ((const float4*)v)[i];
    short4 s4; s4.x = f2bf(a.x); s4.y = f2bf(a.y); s4.z = f2bf(a.z); s4.w = f2bf(a.w);
    ((short4*)vb)[i] = s4;
}

// ---------------- LayerNorm: t = LN(x) --------------------------------------
__global__ __launch_bounds__(256) void ln_kernel(const float* __restrict__ x,
        const float* __restrict__ g, const float* __restrict__ b,
        float* __restrict__ t) {
    int row  = blockIdx.x * 4 + (threadIdx.x >> 6);
    int lane = threadIdx.x & 63;
    const float* xr = x + (size_t)row * H;
    float v0 = xr[lane], v1 = xr[lane + 64];
    float s = v0 + v1;
#pragma unroll
    for (int off = 32; off; off >>= 1) s += __shfl_xor(s, off, 64);
    float mu = s * (1.0f / 128.0f);
    float d0 = v0 - mu, d1 = v1 - mu;
    float q = d0 * d0 + d1 * d1;
#pragma unroll
    for (int off = 32; off; off >>= 1) q += __shfl_xor(q, off, 64);
    float rs = rsqrtf(q * (1.0f / 128.0f) + 1e-5f);
    float* tr = t + (size_t)row * H;
    tr[lane]      = d0 * rs * g[lane]      + b[lane];
    tr[lane + 64] = d1 * rs * g[lane + 64] + b[lane + 64];
}

// ---------------- G1: h1_bf = bf16(ssilu(t @ W1 + b1))  [N,128]x[128,128] ---
__global__ __launch_bounds__(256) void g1_mfma(const float* __restrict__ t,
        const short* __restrict__ W1T, const float* __restrict__ b1,
        short* __restrict__ h1_bf) {
    __shared__ short A_l[64 * AST];
    __shared__ short B_l[128 * AST];
    int tid = threadIdx.x;
    int w = tid >> 6, l = tid & 63, lm = l & 15, q = l >> 4;
    int r0 = blockIdx.x * 64;
    const float4* ag = (const float4*)(t + (size_t)r0 * H);
#pragma unroll
    for (int i = 0; i < 8; ++i) {
        int idx = tid + 256 * i;
        float4 a = ag[idx];
        int row = idx >> 5, c4 = idx & 31;
        short4 s4; s4.x = f2bf(a.x); s4.y = f2bf(a.y); s4.z = f2bf(a.z); s4.w = f2bf(a.w);
        *(short4*)&A_l[row * AST + c4 * 4] = s4;
    }
    const short8* wg = (const short8*)W1T;
#pragma unroll
    for (int i = 0; i < 8; ++i) {
        int idx = tid + 256 * i;
        int row = idx >> 4, c8 = idx & 15;
        *(short8*)&B_l[row * AST + c8 * 8] = wg[idx];
    }
    __syncthreads();
    short8 bf[2][4];
#pragma unroll
    for (int c = 0; c < 2; ++c)
#pragma unroll
        for (int ks = 0; ks < 4; ++ks)
            bf[c][ks] = *(const short8*)&B_l[((2 * w + c) * 16 + lm) * AST + ks * 32 + q * 8];
    f32x4 acc[4][2];
#pragma unroll
    for (int rt = 0; rt < 4; ++rt) { acc[rt][0] = (f32x4){0.f,0.f,0.f,0.f}; acc[rt][1] = (f32x4){0.f,0.f,0.f,0.f}; }
#pragma unroll
    for (int ks = 0; ks < 4; ++ks)
#pragma unroll
        for (int rt = 0; rt < 4; ++rt) {
            short8 a = *(const short8*)&A_l[(rt * 16 + lm) * AST + ks * 32 + q * 8];
            acc[rt][0] = __builtin_amdgcn_mfma_f32_16x16x32_bf16(a, bf[0][ks], acc[rt][0], 0, 0, 0);
            acc[rt][1] = __builtin_amdgcn_mfma_f32_16x16x32_bf16(a, bf[1][ks], acc[rt][1], 0, 0, 0);
        }
#pragma unroll
    for (int c = 0; c < 2; ++c) {
        int col = (2 * w + c) * 16 + lm;
        float bb = b1[col];
#pragma unroll
        for (int rt = 0; rt < 4; ++rt)
#pragma unroll
            for (int r = 0; r < 4; ++r) {
                int R = r0 + rt * 16 + q * 4 + r;
                h1_bf[(size_t)R * H + col] = f2bf(scaled_silu(acc[rt][c][r] + bb));
            }
    }
}

// ---------------- G2: xh_bf = bf16(h1 @ W2 + b2)  [N,128]x[128,384] ---------
__global__ __launch_bounds__(256) void g2_mfma(const short* __restrict__ h1_bf,
        const short* __restrict__ W2T, const float* __restrict__ b2,
        short* __restrict__ xh_bf) {
    __shared__ short A_l[64 * AST];
    __shared__ short B_l[128 * AST];
    int tid = threadIdx.x;
    int w = tid >> 6, l = tid & 63, lm = l & 15, q = l >> 4;
    int r0 = blockIdx.x * 64;
    const short8* ag = (const short8*)(h1_bf + (size_t)r0 * H);
#pragma unroll
    for (int i = 0; i < 4; ++i) {
        int idx = tid + 256 * i;
        int row = idx >> 4, c8 = idx & 15;
        *(short8*)&A_l[row * AST + c8 * 8] = ag[idx];
    }
    for (int s = 0; s < 3; ++s) {
        __syncthreads();
        const short8* wg = (const short8*)(W2T + (size_t)s * 128 * 128);
#pragma unroll
        for (int i = 0; i < 8; ++i) {
            int idx = tid + 256 * i;
            int row = idx >> 4, c8 = idx & 15;
            *(short8*)&B_l[row * AST + c8 * 8] = wg[idx];
        }
        __syncthreads();
        short8 bf[2][4];
#pragma unroll
        for (int c = 0; c < 2; ++c)
#pragma unroll
            for (int ks = 0; ks < 4; ++ks)
                bf[c][ks] = *(const short8*)&B_l[((2 * w + c) * 16 + lm) * AST + ks * 32 + q * 8];
        f32x4 acc[4][2];
#pragma unroll
        for (int rt = 0; rt < 4; ++rt) { acc[rt][0] = (f32x4){0.f,0.f,0.f,0.f}; acc[rt][1] = (f32x4){0.f,0.f,0.f,0.f}; }
#pragma unroll
        for (int ks = 0; ks < 4; ++ks)
#pragma unroll
            for (int rt = 0; rt < 4; ++rt) {
                short8 a = *(const short8*)&A_l[(rt * 16 + lm) * AST + ks * 32 + q * 8];
                acc[rt][0] = __builtin_amdgcn_mfma_f32_16x16x32_bf16(a, bf[0][ks], acc[rt][0], 0, 0, 0);
                acc[rt][1] = __builtin_amdgcn_mfma_f32_16x16x32_bf16(a, bf[1][ks], acc[rt][1], 0, 0, 0);
            }
#pragma unroll
        for (int c = 0; c < 2; ++c) {
            int col = (2 * w + c) * 16 + lm;
            float bb = b2[s * H + col];
#pragma unroll
            for (int rt = 0; rt < 4; ++rt)
#pragma unroll
                for (int r = 0; r < 4; ++r) {
                    int R = r0 + rt * 16 + q * 4 + r;
                    xh_bf[(size_t)R * H3 + s * H + col] = f2bf(acc[rt][c][r] + bb);
                }
        }
    }
}

// ---------------- Sort pass 1: histogram of dst -----------------------------
__global__ __launch_bounds__(256) void hist_kernel(const int* __restrict__ eidx,
        int* __restrict__ hist) {
    int e = blockIdx.x * 256 + threadIdx.x;
    atomicAdd(&hist[eidx[NE + e]], 1);
}

// ---------------- Sort pass 2: exclusive scan of 32768 counts ---------------
__global__ __launch_bounds__(1024) void scan_kernel(const int* __restrict__ hist,
        int* __restrict__ row_ptr, int* __restrict__ cursor) {
    __shared__ int sc[1024];
    int t = threadIdx.x;
    int base = t * 32;
    int v[32];
    int s = 0;
#pragma unroll
    for (int i = 0; i < 32; ++i) {
        int tmp = hist[base + i];
        v[i] = s;
        s += tmp;
    }
    sc[t] = s;
    __syncthreads();
    for (int off = 1; off < 1024; off <<= 1) {
        int a = sc[t];
        int b = (t >= off) ? sc[t - off] : 0;
        __syncthreads();
        sc[t] = a + b;
        __syncthreads();
    }
    int excl = sc[t] - s;
#pragma unroll
    for (int i = 0; i < 32; ++i) {
        int val = excl + v[i];
        row_ptr[base + i] = val;
        cursor[base + i] = val;
    }
    if (t == 0) row_ptr[32768] = NE;
}

// ---------------- Sort pass 3: scatter edges into dst-sorted order ----------
__global__ __launch_bounds__(256) void scatter_kernel(const int* __restrict__ eidx,
        const float* __restrict__ evec, int* __restrict__ cursor,
        int* __restrict__ perm, int* __restrict__ srcs_s, int* __restrict__ dsts_s,
        float* __restrict__ ev_s) {
    int e = blockIdx.x * 256 + threadIdx.x;
    int d = eidx[NE + e];
    int pos = atomicAdd(&cursor[d], 1);
    perm[pos]   = e;
    srcs_s[pos] = eidx[e];
    dsts_s[pos] = d;
    ev_s[pos * 3 + 0] = evec[e * 3 + 0];
    ev_s[pos * 3 + 1] = evec[e * 3 + 1];
    ev_s[pos * 3 + 2] = evec[e * 3 + 2];
}

// ---------------- ee gather: ee_s[pos] = bf16(eembed[perm[pos]]) ------------
// 8 threads per edge; coalesced 256B read per edge, contiguous 128B write.
__global__ __launch_bounds__(256) void eegather_kernel(const int* __restrict__ perm,
        const float* __restrict__ eembed, short* __restrict__ ee_s) {
    int idx = blockIdx.x * 256 + threadIdx.x;  // over NE*8
    int pos = idx >> 3, t = idx & 7;
    int e = perm[pos];
    const float4* src = (const float4*)(eembed + (size_t)e * RB);
    float4 a = src[t * 2];
    float4 b = src[t * 2 + 1];
    short8 s;
    s[0] = f2bf(a.x); s[1] = f2bf(a.y); s[2] = f2bf(a.z); s[3] = f2bf(a.w);
    s[4] = f2bf(b.x); s[5] = f2bf(b.y); s[6] = f2bf(b.z); s[7] = f2bf(b.w);
    ((short8*)(ee_s + (size_t)pos * RB))[t] = s;
}

// ---------------- Wr^T bf16 precompute --------------------------------------
__global__ __launch_bounds__(256) void wrt_kernel(const float* __restrict__ Wr,
        short* __restrict__ WrT16) {
    int i = blockIdx.x * 256 + threadIdx.x;  // over 384*64
    int n = i >> 6, k = i & 63;
    WrT16[i] = f2bf(Wr[(size_t)k * H3 + n]);
}

// ---------------- Edge kernel (CSR + MFMA, bf16 gathers) --------------------
// Round-2 proven body with:
//  (a) staging from pre-sorted bf16 ee_s: one contiguous 2KB load per chunk
//      (no perm indirection, no dependent gather, half the bytes);
//  (b) d1a folded into writeout: x_mid = (x+dx)*c, vec_mid = vec+dvec.
__global__ __launch_bounds__(384) void edge_mfma_kernel(
        const int* __restrict__ row_ptr,
        const int* __restrict__ srcs_s, const int* __restrict__ dsts_s,
        const float* __restrict__ ev_s, const short* __restrict__ ee_s,
        const short* __restrict__ WrT16, const float* __restrict__ br,
        const short* __restrict__ xh_bf, const short* __restrict__ vec_bf,
        const float* __restrict__ xin, const float* __restrict__ vecin,
        float* __restrict__ dx_out, float* __restrict__ dvec_out) {
    __shared__ float accdx[NPB * H];
    __shared__ float accdv[NPB * H3];
    __shared__ short eeL[EB * EEST];
    __shared__ float mst[EB * MSTRIDE];
    __shared__ int   sSrc[EB];
    __shared__ int   sLd[EB];
    __shared__ float sEv[EB][3];
    int j = threadIdx.x;
    int w = j >> 6, l = j & 63;
    int lm = l & 15, q = l >> 4;
    short8 bfrag[4][2];
#pragma unroll
    for (int t = 0; t < 4; ++t)
#pragma unroll
        for (int hf = 0; hf < 2; ++hf)
            bfrag[t][hf] = *(const short8*)(WrT16 +
                ((size_t)(w * 64 + t * 16 + lm) * 64 + q * 8 + hf * 32));
    float brj[4];
#pragma unroll
    for (int t = 0; t < 4; ++t) brj[t] = br[w * 64 + t * 16 + lm];
    float scale = (w < 2) ? 1.0f : ((w < 4) ? (INV_SQRT_3 * INV_SQRT_H) : INV_SQRT_H);
    int n0 = blockIdx.x * NPB;
    for (int i = j; i < NPB * H;  i += 384) accdx[i] = 0.f;
    for (int i = j; i < NPB * H3; i += 384) accdv[i] = 0.f;
    int ib = row_ptr[n0], ie = row_ptr[n0 + NPB];
    int c = j >> 7, hh = j & 127;
    __syncthreads();
    for (int base = ib; base < ie; base += EB) {
        int cnt = min(EB, ie - base);
        // ---- staging: contiguous bf16 rows, no indirection ----
        if (j < 128) {
            int e = j >> 3, c8 = j & 7;
            int i = base + ((e < cnt) ? e : 0);
            *(short8*)(eeL + e * EEST + c8 * 8) =
                ((const short8*)ee_s)[(size_t)i * 8 + c8];
        }
        if (j < EB) {
            int i = base + ((j < cnt) ? j : 0);
            sSrc[j] = srcs_s[i];
            sLd[j]  = dsts_s[i] - n0;
            sEv[j][0] = ev_s[(size_t)i * 3 + 0];
            sEv[j][1] = ev_s[(size_t)i * 3 + 1];
            sEv[j][2] = ev_s[(size_t)i * 3 + 2];
        }
        __syncthreads();
        // ---- xg gathers first (drained by the mst write's vmcnt) ----
        short xg[4][4];
#pragma unroll
        for (int r = 0; r < 4; ++r) {
            const short* xr = xh_bf + (size_t)sSrc[q * 4 + r] * H3 + w * 64 + lm;
#pragma unroll
            for (int t = 0; t < 4; ++t) xg[r][t] = xr[t * 16];
        }
        // ---- vv gathers second: stay in flight across MFMA+mst+barrier ----
        short vv[EB];
#pragma unroll
        for (int e = 0; e < EB; ++e)
            vv[e] = vec_bf[(size_t)sSrc[e] * H3 + j];
        // ---- MFMA: rbfh tile ----
        short8 a0 = *(const short8*)(eeL + lm * EEST + q * 8);
        short8 a1 = *(const short8*)(eeL + lm * EEST + 32 + q * 8);
        f32x4 d[4];
#pragma unroll
        for (int t = 0; t < 4; ++t) {
            d[t] = __builtin_amdgcn_mfma_f32_16x16x32_bf16(a0, bfrag[t][0],
                       (f32x4){0.f, 0.f, 0.f, 0.f}, 0, 0, 0);
            d[t] = __builtin_amdgcn_mfma_f32_16x16x32_bf16(a1, bfrag[t][1], d[t], 0, 0, 0);
        }
        // ---- m = (rbfh + br) * xh[src] * scale -> LDS ----
#pragma unroll
        for (int r = 0; r < 4; ++r) {
            int e = q * 4 + r;
#pragma unroll
            for (int t = 0; t < 4; ++t) {
                float m = (d[t][r] + brj[t]) * bf2f(xg[r][t]) * scale;
                mst[e * MSTRIDE + w * 64 + t * 16 + lm] = m;
            }
        }
        __syncthreads();
        // ---- segmented accumulate (vv already in registers) ----
        int cur = -1; float dva = 0.f, dxa = 0.f;
#pragma unroll
        for (int e = 0; e < EB; ++e) {
            if (e < cnt) {
                float m2 = mst[e * MSTRIDE + H + hh];
                float m3 = mst[e * MSTRIDE + 2 * H + hh];
                int ld = sLd[e];
                if (ld != cur) {
                    if (cur >= 0) {
                        accdv[cur * H3 + j] += dva;
                        if (j < H) accdx[cur * H + j] += dxa;
                    }
                    cur = ld; dva = 0.f; dxa = 0.f;
                }
                dva += bf2f(vv[e]) * m2 + m3 * sEv[e][c];
                if (j < H) dxa += mst[e * MSTRIDE + j];
            }
        }
        if (cur >= 0) {
            accdv[cur * H3 + j] += dva;
            if (j < H) accdx[cur * H + j] += dxa;
        }
        __syncthreads();
    }
    // writeout with d1a folded in: x_mid = (x+dx)*c ; vec_mid = vec+dvec
    for (int i = j; i < NPB * H;  i += 384)
        dx_out[(size_t)n0 * H + i] = (xin[(size_t)n0 * H + i] + accdx[i]) * INV_SQRT_2;
    for (int i = j; i < NPB * H3; i += 384)
        dvec_out[(size_t)n0 * H3 + i] = vecin[(size_t)n0 * H3 + i] + accdv[i];
}

// ---------------- D1: vproj MFMA + dot/norm fused (48 rows = 16 nodes) ------
__global__ __launch_bounds__(256) void d1_vproj(const float* __restrict__ vec_mid,
        const short* __restrict__ WvT, float* __restrict__ vec1,
        float* __restrict__ vdot, short* __restrict__ vnorm_bf) {
    __shared__ short A_l[48 * AST];
    __shared__ short B_l[128 * AST];
    __shared__ float T1[48 * 132];
    __shared__ float T2[48 * 132];
    int tid = threadIdx.x;
    int w = tid >> 6, l = tid & 63, lm = l & 15, q = l >> 4;
    int r0 = blockIdx.x * 48;
    const float4* ag = (const float4*)(vec_mid + (size_t)r0 * H);
#pragma unroll
    for (int i = 0; i < 6; ++i) {
        int idx = tid + 256 * i;
        float4 a = ag[idx];
        int row = idx >> 5, c4 = idx & 31;
        short4 s4; s4.x = f2bf(a.x); s4.y = f2bf(a.y); s4.z = f2bf(a.z); s4.w = f2bf(a.w);
        *(short4*)&A_l[row * AST + c4 * 4] = s4;
    }
    for (int s = 0; s < 2; ++s) {
        __syncthreads();
        const short8* wg = (const short8*)(WvT + (size_t)s * 128 * 128);
#pragma unroll
        for (int i = 0; i < 8; ++i) {
            int idx = tid + 256 * i;
            int row = idx >> 4, c8 = idx & 15;
            *(short8*)&B_l[row * AST + c8 * 8] = wg[idx];
        }
        __syncthreads();
        short8 bf[2][4];
#pragma unroll
        for (int c = 0; c < 2; ++c)
#pragma unroll
            for (int ks = 0; ks < 4; ++ks)
                bf[c][ks] = *(const short8*)&B_l[((2 * w + c) * 16 + lm) * AST + ks * 32 + q * 8];
        f32x4 acc[3][2];
#pragma unroll
        for (int rt = 0; rt < 3; ++rt) { acc[rt][0] = (f32x4){0.f,0.f,0.f,0.f}; acc[rt][1] = (f32x4){0.f,0.f,0.f,0.f}; }
#pragma unroll
        for (int ks = 0; ks < 4; ++ks)
#pragma unroll
            for (int rt = 0; rt < 3; ++rt) {
                short8 a = *(const short8*)&A_l[(rt * 16 + lm) * AST + ks * 32 + q * 8];
                acc[rt][0] = __builtin_amdgcn_mfma_f32_16x16x32_bf16(a, bf[0][ks], acc[rt][0], 0, 0, 0);
                acc[rt][1] = __builtin_amdgcn_mfma_f32_16x16x32_bf16(a, bf[1][ks], acc[rt][1], 0, 0, 0);
            }
        float* T = s ? T2 : T1;
#pragma unroll
        for (int c = 0; c < 2; ++c) {
            int col = (2 * w + c) * 16 + lm;
#pragma unroll
            for (int rt = 0; rt < 3; ++rt)
#pragma unroll
                for (int r = 0; r < 4; ++r) {
                    int lr = rt * 16 + q * 4 + r;
                    float v = acc[rt][c][r];
                    T[lr * 132 + col] = v;
                    if (s == 0) vec1[(size_t)(r0 + lr) * H + col] = v;
                }
        }
    }
    __syncthreads();
    int nb = blockIdx.x * 16;
#pragma unroll
    for (int i = 0; i < 8; ++i) {
        int p = tid + 256 * i;  // 2048 (node, col) pairs
        int k = p & 127, m = p >> 7;
        float d = 0.f, s2 = 0.f;
#pragma unroll
        for (int c = 0; c < 3; ++c) {
            float v1 = T1[(m * 3 + c) * 132 + k];
            float v2 = T2[(m * 3 + c) * 132 + k];
            d += v1 * v2; s2 += v2 * v2;
        }
        vdot[(size_t)(nb + m) * H + k] = d * INV_SQRT_H;
        vnorm_bf[(size_t)(nb + m) * H + k] = f2bf(sqrtf(s2 + 1e-8f));
    }
}

// ---------------- D2a: u_bf = bf16(ssilu([x_mid, vnorm] @ Wu1 + bu1)) -------
__global__ __launch_bounds__(256) void d2a_mfma(const float* __restrict__ xmid,
        const short* __restrict__ vnorm_bf, const short* __restrict__ Wu1T,
        const float* __restrict__ bu1, short* __restrict__ u_bf) {
    __shared__ short A_l[64 * AST];
    __shared__ short B_l[128 * AST];
    int tid = threadIdx.x;
    int w = tid >> 6, l = tid & 63, lm = l & 15, q = l >> 4;
    int r0 = blockIdx.x * 64;
    f32x4 acc[4][2];
#pragma unroll
    for (int rt = 0; rt < 4; ++rt) { acc[rt][0] = (f32x4){0.f,0.f,0.f,0.f}; acc[rt][1] = (f32x4){0.f,0.f,0.f,0.f}; }
    for (int kh = 0; kh < 2; ++kh) {
        __syncthreads();
        if (kh == 0) {
            const float4* ag = (const float4*)(xmid + (size_t)r0 * H);
#pragma unroll
            for (int i = 0; i < 8; ++i) {
                int idx = tid + 256 * i;
                float4 a = ag[idx];
                int row = idx >> 5, c4 = idx & 31;
                short4 s4; s4.x = f2bf(a.x); s4.y = f2bf(a.y); s4.z = f2bf(a.z); s4.w = f2bf(a.w);
                *(short4*)&A_l[row * AST + c4 * 4] = s4;
            }
        } else {
            const short8* ag = (const short8*)(vnorm_bf + (size_t)r0 * H);
#pragma unroll
            for (int i = 0; i < 4; ++i) {
                int idx = tid + 256 * i;
                int row = idx >> 4, c8 = idx & 15;
                *(short8*)&A_l[row * AST + c8 * 8] = ag[idx];
            }
        }
#pragma unroll
        for (int i = 0; i < 8; ++i) {
            int idx = tid + 256 * i;
            int row = idx >> 4, c8 = idx & 15;
            *(short8*)&B_l[row * AST + c8 * 8] = ((const short8*)Wu1T)[row * 32 + kh * 16 + c8];
        }
        __syncthreads();
        short8 bf[2][4];
#pragma unroll
        for (int c = 0; c < 2; ++c)
#pragma unroll
            for (int ks = 0; ks < 4; ++ks)
                bf[c][ks] = *(const short8*)&B_l[((2 * w + c) * 16 + lm) * AST + ks * 32 + q * 8];
#pragma unroll
        for (int ks = 0; ks < 4; ++ks)
#pragma unroll
            for (int rt = 0; rt < 4; ++rt) {
                short8 a = *(const short8*)&A_l[(rt * 16 + lm) * AST + ks * 32 + q * 8];
                acc[rt][0] = __builtin_amdgcn_mfma_f32_16x16x32_bf16(a, bf[0][ks], acc[rt][0], 0, 0, 0);
                acc[rt][1] = __builtin_amdgcn_mfma_f32_16x16x32_bf16(a, bf[1][ks], acc[rt][1], 0, 0, 0);
            }
    }
#pragma unroll
    for (int c = 0; c < 2; ++c) {
        int col = (2 * w + c) * 16 + lm;
        float bb = bu1[col];
#pragma unroll
        for (int rt = 0; rt < 4; ++rt)
#pragma unroll
            for (int r = 0; r < 4; ++r) {
                int R = r0 + rt * 16 + q * 4 + r;
                u_bf[(size_t)R * H + col] = f2bf(scaled_silu(acc[rt][c][r] + bb));
            }
    }
}

// ---------------- D2b: h = u @ Wu2 + bu2; final outputs ---------------------
__global__ __launch_bounds__(256) void d2b_mfma(const short* __restrict__ u_bf,
        const short* __restrict__ Wu2T, const float* __restrict__ bu2,
        const float* __restrict__ vdot, const float* __restrict__ xmid,
        const float* __restrict__ vec_mid, const float* __restrict__ vec1,
        float* __restrict__ out) {
    __shared__ short A_l[64 * AST];
    __shared__ short B_l[128 * AST];
    int tid = threadIdx.x;
    int w = tid >> 6, l = tid & 63, lm = l & 15, q = l >> 4;
    int r0 = blockIdx.x * 64;
    float* out_vec = out;
    float* out_x = out + (size_t)NN * H3;
    const short8* ag = (const short8*)(u_bf + (size_t)r0 * H);
#pragma unroll
    for (int i = 0; i < 4; ++i) {
        int idx = tid + 256 * i;
        int row = idx >> 4, c8 = idx & 15;
        *(short8*)&A_l[row * AST + c8 * 8] = ag[idx];
    }
    // stage slice 0, keep frags; stage slice 1, keep frags; dual K-loop
    short8 bf0[2][4], bf1[2][4];
    __syncthreads();
    {
        const short8* wg = (const short8*)Wu2T;
#pragma unroll
        for (int i = 0; i < 8; ++i) {
            int idx = tid + 256 * i;
            int row = idx >> 4, c8 = idx & 15;
            *(short8*)&B_l[row * AST + c8 * 8] = wg[idx];
        }
    }
    __syncthreads();
#pragma unroll
    for (int c = 0; c < 2; ++c)
#pragma unroll
        for (int ks = 0; ks < 4; ++ks)
            bf0[c][ks] = *(const short8*)&B_l[((2 * w + c) * 16 + lm) * AST + ks * 32 + q * 8];
    __syncthreads();
    {
        const short8* wg = (const short8*)(Wu2T + 128 * 128);
#pragma unroll
        for (int i = 0; i < 8; ++i) {
            int idx = tid + 256 * i;
            int row = idx >> 4, c8 = idx & 15;
            *(short8*)&B_l[row * AST + c8 * 8] = wg[idx];
        }
    }
    __syncthreads();
#pragma unroll
    for (int c = 0; c < 2; ++c)
#pragma unroll
        for (int ks = 0; ks < 4; ++ks)
            bf1[c][ks] = *(const short8*)&B_l[((2 * w + c) * 16 + lm) * AST + ks * 32 + q * 8];
    f32x4 acc0[4][2], acc1[4][2];
#pragma unroll
    for (int rt = 0; rt < 4; ++rt) {
        acc0[rt][0] = (f32x4){0.f,0.f,0.f,0.f}; acc0[rt][1] = (f32x4){0.f,0.f,0.f,0.f};
        acc1[rt][0] = (f32x4){0.f,0.f,0.f,0.f}; acc1[rt][1] = (f32x4){0.f,0.f,0.f,0.f};
    }
#pragma unroll
    for (int ks = 0; ks < 4; ++ks)
#pragma unroll
        for (int rt = 0; rt < 4; ++rt) {
            short8 a = *(const short8*)&A_l[(rt * 16 + lm) * AST + ks * 32 + q * 8];
            acc0[rt][0] = __builtin_amdgcn_mfma_f32_16x16x32_bf16(a, bf0[0][ks], acc0[rt][0], 0, 0, 0);
            acc0[rt][1] = __builtin_amdgcn_mfma_f32_16x16x32_bf16(a, bf0[1][ks], acc0[rt][1], 0, 0, 0);
            acc1[rt][0] = __builtin_amdgcn_mfma_f32_16x16x32_bf16(a, bf1[0][ks], acc1[rt][0], 0, 0, 0);
            acc1[rt][1] = __builtin_amdgcn_mfma_f32_16x16x32_bf16(a, bf1[1][ks], acc1[rt][1], 0, 0, 0);
        }
    // epilogue: out_x = x_mid + (xv1 + xv2*vdot)*INV_SQRT_2
#pragma unroll
    for (int c = 0; c < 2; ++c) {
        int col = (2 * w + c) * 16 + lm;
        float bb0 = bu2[col], bb1 = bu2[H + col];
#pragma unroll
        for (int rt = 0; rt < 4; ++rt)
#pragma unroll
            for (int r = 0; r < 4; ++r) {
                int R = r0 + rt * 16 + q * 4 + r;
                float xv1 = acc0[rt][c][r] + bb0;
                float xv2 = acc1[rt][c][r] + bb1;
                float dx2 = (xv1 + xv2 * vdot[(size_t)R * H + col]) * INV_SQRT_2;
                out_x[(size_t)R * H + col] = xmid[(size_t)R * H + col] + dx2;
            }
    }
    // slice 2 (xv3) -> out_vec
    __syncthreads();
    {
        const short8* wg = (const short8*)(Wu2T + 2 * 128 * 128);
#pragma unroll
        for (int i = 0; i < 8; ++i) {
            int idx = tid + 256 * i;
            int row = idx >> 4, c8 = idx & 15;
            *(short8*)&B_l[row * AST + c8 * 8] = wg[idx];
        }
    }
    __syncthreads();
#pragma unroll
    for (int c = 0; c < 2; ++c)
#pragma unroll
        for (int ks = 0; ks < 4; ++ks)
            bf0[c][ks] = *(const short8*)&B_l[((2 * w + c) * 16 + lm) * AST + ks * 32 + q * 8];
#pragma unroll
    for (int rt = 0; rt < 4; ++rt) { acc0[rt][0] = (f32x4){0.f,0.f,0.f,0.f}; acc0[rt][1] = (f32x4){0.f,0.f,0.f,0.f}; }
#pragma unroll
    for (int ks = 0; ks < 4; ++ks)
#pragma unroll
        for (int rt = 0; rt < 4; ++rt) {
            short8 a = *(const short8*)&A_l[(rt * 16 + lm) * AST + ks * 32 + q * 8];
            acc0[rt][0] = __builtin_amdgcn_mfma_f32_16x16x32_bf16(a, bf0[0][ks], acc0[rt][0], 0, 0, 0);
            acc0[rt][1] = __builtin_amdgcn_mfma_f32_16x16x32_bf16(a, bf0[1][ks], acc0[rt][1], 0, 0, 0);
        }
#pragma unroll
    for (int c = 0; c < 2; ++c) {
        int col = (2 * w + c) * 16 + lm;
        float bb2 = bu2[2 * H + col];
#pragma unroll
        for (int rt = 0; rt < 4; ++rt)
#pragma unroll
            for (int r = 0; r < 4; ++r) {
                int R = r0 + rt * 16 + q * 4 + r;
                float xv3 = acc0[rt][c][r] + bb2;
#pragma unroll
                for (int c3 = 0; c3 < 3; ++c3) {
                    size_t idx = (size_t)R * H3 + c3 * H + col;
                    out_vec[idx] = vec_mid[idx] + xv3 * vec1[idx];
                }
            }
    }
}

extern "C" void kernel_launch(void* const* d_in, const int* in_sizes, int n_in,
                              void* d_out, int out_size, void* d_ws, size_t ws_size,
                              hipStream_t stream) {
    const float* x    = (const float*)d_in[0];
    const float* vec  = (const float*)d_in[1];
    const int*   eidx = (const int*)d_in[2];
    const float* eemb = (const float*)d_in[3];
    const float* evec = (const float*)d_in[4];
    const float* lng  = (const float*)d_in[5];
    const float* lnb  = (const float*)d_in[6];
    const float* W1   = (const float*)d_in[7];
    const float* b1   = (const float*)d_in[8];
    const float* W2   = (const float*)d_in[9];
    const float* b2   = (const float*)d_in[10];
    const float* Wr   = (const float*)d_in[11];
    const float* br   = (const float*)d_in[12];
    const float* Wv   = (const float*)d_in[13];
    const float* Wu1  = (const float*)d_in[14];
    const float* bu1  = (const float*)d_in[15];
    const float* Wu2  = (const float*)d_in[16];
    const float* bu2  = (const float*)d_in[17];

    // workspace layout:
    // B0: N*384 f32 : xh_bf16 (as shorts) -> vec1 f32
    // B1: N*384 f32 : vec_mid (edge kernel writes directly)
    // B2: N*128 f32 : t(LN) -> x_mid (edge kernel writes directly)
    // B3: N*128 f32 : h1_bf16 (as shorts) -> vec_dot f32
    // B4: N*128 f32 : [sort scratch + WrT16] -> vnorm_bf16 + u_bf16
    // B5: vec_bf16 (N*384 shorts) + bf16 transposed weights
    // ee_sorted (NE*64 bf16 = 67MB) lives in d_out (overwritten by d2b later)
    float* B0 = (float*)d_ws;
    float* B1 = B0 + (size_t)NN * H3;
    float* B2 = B1 + (size_t)NN * H3;
    float* B3 = B2 + (size_t)NN * H;
    float* B4 = B3 + (size_t)NN * H;
    short* B5 = (short*)(B4 + (size_t)NN * H);
    float* out = (float*)d_out;
    short* ee_s = (short*)d_out;   // NE*64 shorts == out_size bytes exactly

    int* row_ptr = (int*)B4;
    int* cursor  = row_ptr + 32772;
    int* perm    = cursor + 32768;
    int* srcs_s  = perm + NE;
    int* dsts_s  = srcs_s + NE;
    float* ev_s  = (float*)(dsts_s + NE);
    short* WrT16 = (short*)(ev_s + (size_t)NE * 3);

    short* vec_bf = B5;
    short* W1T  = vec_bf + (size_t)NN * H3;
    short* W2T  = W1T + 128 * 128;
    short* WvT  = W2T + 128 * 384;
    short* Wu1T = WvT + 128 * 256;
    short* Wu2T = Wu1T + 256 * 128;

    short* xh_bf    = (short*)B0;
    short* h1_bf    = (short*)B3;
    short* vnorm_bf = (short*)B4;
    short* u_bf     = vnorm_bf + (size_t)NN * H;

    // weight conversions + vec bf16 copy
    cvtT_kernel<<<64,  256, 0, stream>>>(W1,  W1T,  128, 128);
    cvtT_kernel<<<192, 256, 0, stream>>>(W2,  W2T,  128, 384);
    cvtT_kernel<<<128, 256, 0, stream>>>(Wv,  WvT,  128, 256);
    cvtT_kernel<<<128, 256, 0, stream>>>(Wu1, Wu1T, 256, 128);
    cvtT_kernel<<<192, 256, 0, stream>>>(Wu2, Wu2T, 128, 384);
    wrt_kernel<<<(H3 * RB) / 256, 256, 0, stream>>>(Wr, WrT16);
    veccvt_kernel<<<(NN * H3 / 4) / 256, 256, 0, stream>>>(vec, vec_bf);

    // node message path
    ln_kernel<<<NN / 4, 256, 0, stream>>>(x, lng, lnb, B2);
    g1_mfma<<<NN / 64, 256, 0, stream>>>(B2, W1T, b1, h1_bf);
    g2_mfma<<<NN / 64, 256, 0, stream>>>(h1_bf, W2T, b2, xh_bf);

    // dst counting sort -> CSR, then pre-gather eembed into sorted bf16 rows
    hipMemsetAsync(row_ptr, 0, 32768 * sizeof(int), stream);
    hist_kernel<<<NE / 256, 256, 0, stream>>>(eidx, row_ptr);
    scan_kernel<<<1, 1024, 0, stream>>>(row_ptr, row_ptr, cursor);
    scatter_kernel<<<NE / 256, 256, 0, stream>>>(eidx, evec, cursor, perm, srcs_s, dsts_s, ev_s);
    eegather_kernel<<<(NE * 8) / 256, 256, 0, stream>>>(perm, eemb, ee_s);

    // fused edge message + segment reduce + d1a fold
    // (x_mid -> B2, vec_mid -> B1)
    edge_mfma_kernel<<<NN / NPB, 384, 0, stream>>>(row_ptr, srcs_s, dsts_s, ev_s,
                                                   ee_s, WrT16, br, xh_bf, vec_bf,
                                                   x, vec, B2, B1);

    // update path
    d1_vproj<<<(NN * 3) / 48, 256, 0, stream>>>(B1, WvT, B0, B3, vnorm_bf);
    d2a_mfma<<<NN / 64, 256, 0, stream>>>(B2, vnorm_bf, Wu1T, bu1, u_bf);
    d2b_mfma<<<NN / 64, 256, 0, stream>>>(u_bf, Wu2T, bu2, B3, B2, B1, B0, out);
}

// Round 5
// 871.537 us; speedup vs baseline: 1.1700x; 1.0752x over previous
//
#include <hip/hip_runtime.h>
#include <cstdint>
#include <cstddef>

#define NN 32768
#define NE 524288
#define H  128
#define H3 384
#define RB 64
#define EB 16
#define NPB 4        // dst nodes per block in edge kernel
#define EEST 72      // padded LDS row stride (shorts) for ee tile
#define MSTRIDE 388  // padded LDS row stride (floats) for mst
#define AST 136      // padded LDS row stride (shorts) for 128-wide bf16 tiles

#define INV_SQRT_3 0.5773502691896258f
#define INV_SQRT_H 0.08838834764831845f
#define INV_SQRT_2 0.7071067811865476f

typedef __attribute__((ext_vector_type(8))) short short8;
typedef __attribute__((ext_vector_type(4))) float f32x4;

__device__ __forceinline__ float scaled_silu(float v) {
    return v * (1.0f / 0.6f) / (1.0f + __expf(-v));
}
__device__ __forceinline__ short f2bf(float f) {
    uint32_t u = __float_as_uint(f);
    uint32_t r = (u + 0x7FFFu + ((u >> 16) & 1u)) >> 16;
    return (short)r;
}
__device__ __forceinline__ float bf2f(short s) {
    return __uint_as_float(((uint32_t)(uint16_t)s) << 16);
}

// ---------------- weight transpose+bf16: WT[m][k] = bf16(W[k][m]) -----------
__global__ __launch_bounds__(256) void cvtT_kernel(const float* __restrict__ W,
        short* __restrict__ WT, int K, int M) {
    int i = blockIdx.x * 256 + threadIdx.x;  // i < K*M
    int k = i / M, m = i % M;
    WT[(size_t)m * K + k] = f2bf(W[(size_t)k * M + m]);
}

// ---------------- vec -> bf16 copy ------------------------------------------
__global__ __launch_bounds__(256) void veccvt_kernel(const float* __restrict__ v,
        short* __restrict__ vb) {
    int i = blockIdx.x * 256 + threadIdx.x;  // over N*H3/4
    float4 a = ((const float4*)v)[i];
    short4 s4; s4.x = f2bf(a.x); s4.y = f2bf(a.y); s4.z = f2bf(a.z); s4.w = f2bf(a.w);
    ((short4*)vb)[i] = s4;
}

// ---------------- LayerNorm: t = LN(x) --------------------------------------
__global__ __launch_bounds__(256) void ln_kernel(const float* __restrict__ x,
        const float* __restrict__ g, const float* __restrict__ b,
        float* __restrict__ t) {
    int row  = blockIdx.x * 4 + (threadIdx.x >> 6);
    int lane = threadIdx.x & 63;
    const float* xr = x + (size_t)row * H;
    float v0 = xr[lane], v1 = xr[lane + 64];
    float s = v0 + v1;
#pragma unroll
    for (int off = 32; off; off >>= 1) s += __shfl_xor(s, off, 64);
    float mu = s * (1.0f / 128.0f);
    float d0 = v0 - mu, d1 = v1 - mu;
    float q = d0 * d0 + d1 * d1;
#pragma unroll
    for (int off = 32; off; off >>= 1) q += __shfl_xor(q, off, 64);
    float rs = rsqrtf(q * (1.0f / 128.0f) + 1e-5f);
    float* tr = t + (size_t)row * H;
    tr[lane]      = d0 * rs * g[lane]      + b[lane];
    tr[lane + 64] = d1 * rs * g[lane + 64] + b[lane + 64];
}

// ---------------- G1: h1_bf = bf16(ssilu(t @ W1 + b1))  [N,128]x[128,128] ---
__global__ __launch_bounds__(256) void g1_mfma(const float* __restrict__ t,
        const short* __restrict__ W1T, const float* __restrict__ b1,
        short* __restrict__ h1_bf) {
    __shared__ short A_l[64 * AST];
    __shared__ short B_l[128 * AST];
    int tid = threadIdx.x;
    int w = tid >> 6, l = tid & 63, lm = l & 15, q = l >> 4;
    int r0 = blockIdx.x * 64;
    const float4* ag = (const float4*)(t + (size_t)r0 * H);
#pragma unroll
    for (int i = 0; i < 8; ++i) {
        int idx = tid + 256 * i;
        float4 a = ag[idx];
        int row = idx >> 5, c4 = idx & 31;
        short4 s4; s4.x = f2bf(a.x); s4.y = f2bf(a.y); s4.z = f2bf(a.z); s4.w = f2bf(a.w);
        *(short4*)&A_l[row * AST + c4 * 4] = s4;
    }
    const short8* wg = (const short8*)W1T;
#pragma unroll
    for (int i = 0; i < 8; ++i) {
        int idx = tid + 256 * i;
        int row = idx >> 4, c8 = idx & 15;
        *(short8*)&B_l[row * AST + c8 * 8] = wg[idx];
    }
    __syncthreads();
    short8 bf[2][4];
#pragma unroll
    for (int c = 0; c < 2; ++c)
#pragma unroll
        for (int ks = 0; ks < 4; ++ks)
            bf[c][ks] = *(const short8*)&B_l[((2 * w + c) * 16 + lm) * AST + ks * 32 + q * 8];
    f32x4 acc[4][2];
#pragma unroll
    for (int rt = 0; rt < 4; ++rt) { acc[rt][0] = (f32x4){0.f,0.f,0.f,0.f}; acc[rt][1] = (f32x4){0.f,0.f,0.f,0.f}; }
#pragma unroll
    for (int ks = 0; ks < 4; ++ks)
#pragma unroll
        for (int rt = 0; rt < 4; ++rt) {
            short8 a = *(const short8*)&A_l[(rt * 16 + lm) * AST + ks * 32 + q * 8];
            acc[rt][0] = __builtin_amdgcn_mfma_f32_16x16x32_bf16(a, bf[0][ks], acc[rt][0], 0, 0, 0);
            acc[rt][1] = __builtin_amdgcn_mfma_f32_16x16x32_bf16(a, bf[1][ks], acc[rt][1], 0, 0, 0);
        }
#pragma unroll
    for (int c = 0; c < 2; ++c) {
        int col = (2 * w + c) * 16 + lm;
        float bb = b1[col];
#pragma unroll
        for (int rt = 0; rt < 4; ++rt)
#pragma unroll
            for (int r = 0; r < 4; ++r) {
                int R = r0 + rt * 16 + q * 4 + r;
                h1_bf[(size_t)R * H + col] = f2bf(scaled_silu(acc[rt][c][r] + bb));
            }
    }
}

// ---------------- G2: xh_bf = bf16(h1 @ W2 + b2)  [N,128]x[128,384] ---------
__global__ __launch_bounds__(256) void g2_mfma(const short* __restrict__ h1_bf,
        const short* __restrict__ W2T, const float* __restrict__ b2,
        short* __restrict__ xh_bf) {
    __shared__ short A_l[64 * AST];
    __shared__ short B_l[128 * AST];
    int tid = threadIdx.x;
    int w = tid >> 6, l = tid & 63, lm = l & 15, q = l >> 4;
    int r0 = blockIdx.x * 64;
    const short8* ag = (const short8*)(h1_bf + (size_t)r0 * H);
#pragma unroll
    for (int i = 0; i < 4; ++i) {
        int idx = tid + 256 * i;
        int row = idx >> 4, c8 = idx & 15;
        *(short8*)&A_l[row * AST + c8 * 8] = ag[idx];
    }
    for (int s = 0; s < 3; ++s) {
        __syncthreads();
        const short8* wg = (const short8*)(W2T + (size_t)s * 128 * 128);
#pragma unroll
        for (int i = 0; i < 8; ++i) {
            int idx = tid + 256 * i;
            int row = idx >> 4, c8 = idx & 15;
            *(short8*)&B_l[row * AST + c8 * 8] = wg[idx];
        }
        __syncthreads();
        short8 bf[2][4];
#pragma unroll
        for (int c = 0; c < 2; ++c)
#pragma unroll
            for (int ks = 0; ks < 4; ++ks)
                bf[c][ks] = *(const short8*)&B_l[((2 * w + c) * 16 + lm) * AST + ks * 32 + q * 8];
        f32x4 acc[4][2];
#pragma unroll
        for (int rt = 0; rt < 4; ++rt) { acc[rt][0] = (f32x4){0.f,0.f,0.f,0.f}; acc[rt][1] = (f32x4){0.f,0.f,0.f,0.f}; }
#pragma unroll
        for (int ks = 0; ks < 4; ++ks)
#pragma unroll
            for (int rt = 0; rt < 4; ++rt) {
                short8 a = *(const short8*)&A_l[(rt * 16 + lm) * AST + ks * 32 + q * 8];
                acc[rt][0] = __builtin_amdgcn_mfma_f32_16x16x32_bf16(a, bf[0][ks], acc[rt][0], 0, 0, 0);
                acc[rt][1] = __builtin_amdgcn_mfma_f32_16x16x32_bf16(a, bf[1][ks], acc[rt][1], 0, 0, 0);
            }
#pragma unroll
        for (int c = 0; c < 2; ++c) {
            int col = (2 * w + c) * 16 + lm;
            float bb = b2[s * H + col];
#pragma unroll
            for (int rt = 0; rt < 4; ++rt)
#pragma unroll
                for (int r = 0; r < 4; ++r) {
                    int R = r0 + rt * 16 + q * 4 + r;
                    xh_bf[(size_t)R * H3 + s * H + col] = f2bf(acc[rt][c][r] + bb);
                }
        }
    }
}

// ---------------- Sort pass 1: histogram of dst -----------------------------
__global__ __launch_bounds__(256) void hist_kernel(const int* __restrict__ eidx,
        int* __restrict__ hist) {
    int e = blockIdx.x * 256 + threadIdx.x;
    atomicAdd(&hist[eidx[NE + e]], 1);
}

// ---------------- Sort pass 2: exclusive scan of 32768 counts ---------------
__global__ __launch_bounds__(1024) void scan_kernel(const int* __restrict__ hist,
        int* __restrict__ row_ptr, int* __restrict__ cursor) {
    __shared__ int sc[1024];
    int t = threadIdx.x;
    int base = t * 32;
    int v[32];
    int s = 0;
#pragma unroll
    for (int i = 0; i < 32; ++i) {
        int tmp = hist[base + i];
        v[i] = s;
        s += tmp;
    }
    sc[t] = s;
    __syncthreads();
    for (int off = 1; off < 1024; off <<= 1) {
        int a = sc[t];
        int b = (t >= off) ? sc[t - off] : 0;
        __syncthreads();
        sc[t] = a + b;
        __syncthreads();
    }
    int excl = sc[t] - s;
#pragma unroll
    for (int i = 0; i < 32; ++i) {
        int val = excl + v[i];
        row_ptr[base + i] = val;
        cursor[base + i] = val;
    }
    if (t == 0) row_ptr[32768] = NE;
}

// ---------------- Sort pass 3: scatter edges into dst-sorted order ----------
__global__ __launch_bounds__(256) void scatter_kernel(const int* __restrict__ eidx,
        const float* __restrict__ evec, int* __restrict__ cursor,
        int* __restrict__ perm, int* __restrict__ srcs_s, int* __restrict__ dsts_s,
        float* __restrict__ ev_s) {
    int e = blockIdx.x * 256 + threadIdx.x;
    int d = eidx[NE + e];
    int pos = atomicAdd(&cursor[d], 1);
    perm[pos]   = e;
    srcs_s[pos] = eidx[e];
    dsts_s[pos] = d;
    ev_s[pos * 3 + 0] = evec[e * 3 + 0];
    ev_s[pos * 3 + 1] = evec[e * 3 + 1];
    ev_s[pos * 3 + 2] = evec[e * 3 + 2];
}

// ---------------- ee gather: ee_s[pos] = bf16(eembed[perm[pos]]) ------------
__global__ __launch_bounds__(256) void eegather_kernel(const int* __restrict__ perm,
        const float* __restrict__ eembed, short* __restrict__ ee_s) {
    int idx = blockIdx.x * 256 + threadIdx.x;  // over NE*8
    int pos = idx >> 3, t = idx & 7;
    int e = perm[pos];
    const float4* src = (const float4*)(eembed + (size_t)e * RB);
    float4 a = src[t * 2];
    float4 b = src[t * 2 + 1];
    short8 s;
    s[0] = f2bf(a.x); s[1] = f2bf(a.y); s[2] = f2bf(a.z); s[3] = f2bf(a.w);
    s[4] = f2bf(b.x); s[5] = f2bf(b.y); s[6] = f2bf(b.z); s[7] = f2bf(b.w);
    ((short8*)(ee_s + (size_t)pos * RB))[t] = s;
}

// ---------------- Wr^T bf16 precompute --------------------------------------
__global__ __launch_bounds__(256) void wrt_kernel(const float* __restrict__ Wr,
        short* __restrict__ WrT16) {
    int i = blockIdx.x * 256 + threadIdx.x;  // over 384*64
    int n = i >> 6, k = i & 63;
    WrT16[i] = f2bf(Wr[(size_t)k * H3 + n]);
}

// ---------------- Edge kernel (CSR + MFMA, bf16 gathers) --------------------
// Round-4 body + two changes:
//  (1) accumulate-phase LDS reads (m1/m2/m3/sEv/sLd) batched unguarded into
//      registers in two 8-edge sub-batches -> segment loop is register-only
//      (fixes the serialized conditional ds_read chain).
//  (2) double-buffered ee+meta staging, 2 barriers/chunk: next chunk's loads
//      issue at phase top, LDS writes land after the accumulate.
__global__ __launch_bounds__(384, 4) void edge_mfma_kernel(
        const int* __restrict__ row_ptr,
        const int* __restrict__ srcs_s, const int* __restrict__ dsts_s,
        const float* __restrict__ ev_s, const short* __restrict__ ee_s,
        const short* __restrict__ WrT16, const float* __restrict__ br,
        const short* __restrict__ xh_bf, const short* __restrict__ vec_bf,
        const float* __restrict__ xin, const float* __restrict__ vecin,
        float* __restrict__ dx_out, float* __restrict__ dvec_out) {
    __shared__ float accdx[NPB * H];
    __shared__ float accdv[NPB * H3];
    __shared__ short eeL[2][EB * EEST];
    __shared__ float mst[EB * MSTRIDE];
    __shared__ int   sSrc[2][EB];
    __shared__ int   sLd[2][EB];
    __shared__ float sEv[2][EB][3];
    int j = threadIdx.x;
    int w = j >> 6, l = j & 63;
    int lm = l & 15, q = l >> 4;
    short8 bfrag[4][2];
#pragma unroll
    for (int t = 0; t < 4; ++t)
#pragma unroll
        for (int hf = 0; hf < 2; ++hf)
            bfrag[t][hf] = *(const short8*)(WrT16 +
                ((size_t)(w * 64 + t * 16 + lm) * 64 + q * 8 + hf * 32));
    float brj[4];
#pragma unroll
    for (int t = 0; t < 4; ++t) brj[t] = br[w * 64 + t * 16 + lm];
    float scale = (w < 2) ? 1.0f : ((w < 4) ? (INV_SQRT_3 * INV_SQRT_H) : INV_SQRT_H);
    int n0 = blockIdx.x * NPB;
    for (int i = j; i < NPB * H;  i += 384) accdx[i] = 0.f;
    for (int i = j; i < NPB * H3; i += 384) accdv[i] = 0.f;
    int ib = row_ptr[n0], ie = row_ptr[n0 + NPB];
    int c = j >> 7, hh = j & 127;

    // prologue: stage chunk 0 into buffer 0
    if (ib < ie) {
        int cnt0 = min(EB, ie - ib);
        if (j < 128) {
            int e = j >> 3, c8 = j & 7;
            int i = ib + ((e < cnt0) ? e : 0);
            *(short8*)(eeL[0] + e * EEST + c8 * 8) =
                ((const short8*)ee_s)[(size_t)i * 8 + c8];
        }
        if (j < EB) {
            int i = ib + ((j < cnt0) ? j : 0);
            sSrc[0][j] = srcs_s[i];
            sLd[0][j]  = dsts_s[i] - n0;
            sEv[0][j][0] = ev_s[(size_t)i * 3 + 0];
            sEv[0][j][1] = ev_s[(size_t)i * 3 + 1];
            sEv[0][j][2] = ev_s[(size_t)i * 3 + 2];
        }
    }

    int bsel = 0;
    for (int base = ib; base < ie; base += EB) {
        int cnt = min(EB, ie - base);
        __syncthreads();   // BAR-A: eeL[bsel]+meta ready; mst free
        // ---- issue next chunk's staging loads (independent, contiguous) ----
        int nbase = base + EB;
        int hn = nbase < ie;
        short8 ereg = {0,0,0,0,0,0,0,0};
        int msrc = 0, mdst = n0; float me0 = 0.f, me1 = 0.f, me2 = 0.f;
        if (hn) {
            int cntn = min(EB, ie - nbase);
            if (j < 128) {
                int e = j >> 3, c8 = j & 7;
                int i = nbase + ((e < cntn) ? e : 0);
                ereg = ((const short8*)ee_s)[(size_t)i * 8 + c8];
            }
            if (j < EB) {
                int i = nbase + ((j < cntn) ? j : 0);
                msrc = srcs_s[i]; mdst = dsts_s[i];
                me0 = ev_s[(size_t)i * 3 + 0];
                me1 = ev_s[(size_t)i * 3 + 1];
                me2 = ev_s[(size_t)i * 3 + 2];
            }
        }
        // ---- xg gathers (drained by the mst write's vmcnt) ----
        short xg[4][4];
#pragma unroll
        for (int r = 0; r < 4; ++r) {
            const short* xr = xh_bf + (size_t)sSrc[bsel][q * 4 + r] * H3 + w * 64 + lm;
#pragma unroll
            for (int t = 0; t < 4; ++t) xg[r][t] = xr[t * 16];
        }
        // ---- vv gathers: stay in flight across MFMA+mst+barrier ----
        short vv[EB];
#pragma unroll
        for (int e = 0; e < EB; ++e)
            vv[e] = vec_bf[(size_t)sSrc[bsel][e] * H3 + j];
        // ---- MFMA: rbfh tile ----
        const short* eeC = eeL[bsel];
        short8 a0 = *(const short8*)(eeC + lm * EEST + q * 8);
        short8 a1 = *(const short8*)(eeC + lm * EEST + 32 + q * 8);
        f32x4 d[4];
#pragma unroll
        for (int t = 0; t < 4; ++t) {
            d[t] = __builtin_amdgcn_mfma_f32_16x16x32_bf16(a0, bfrag[t][0],
                       (f32x4){0.f, 0.f, 0.f, 0.f}, 0, 0, 0);
            d[t] = __builtin_amdgcn_mfma_f32_16x16x32_bf16(a1, bfrag[t][1], d[t], 0, 0, 0);
        }
        // ---- m = (rbfh + br) * xh[src] * scale -> LDS ----
#pragma unroll
        for (int r = 0; r < 4; ++r) {
            int e = q * 4 + r;
#pragma unroll
            for (int t = 0; t < 4; ++t) {
                float m = (d[t][r] + brj[t]) * bf2f(xg[r][t]) * scale;
                mst[e * MSTRIDE + w * 64 + t * 16 + lm] = m;
            }
        }
        __syncthreads();   // BAR-B: mst visible; eeL[bsel] fully consumed
        // ---- segmented accumulate: batched unguarded LDS reads, 2x8 ----
        int cur = -1; float dva = 0.f, dxa = 0.f;
#pragma unroll
        for (int half = 0; half < 2; ++half) {
            float m1g[8], m2g[8], m3g[8], evg[8];
            int ldg[8];
#pragma unroll
            for (int u = 0; u < 8; ++u) {
                int e = half * 8 + u;
                m1g[u] = mst[e * MSTRIDE + j];          // j<388: in-bounds
                m2g[u] = mst[e * MSTRIDE + H + hh];
                m3g[u] = mst[e * MSTRIDE + 2 * H + hh];
                evg[u] = sEv[bsel][e][c];
                ldg[u] = sLd[bsel][e];
            }
#pragma unroll
            for (int u = 0; u < 8; ++u) {
                int e = half * 8 + u;
                if (e < cnt) {
                    int ld = ldg[u];
                    if (ld != cur) {
                        if (cur >= 0) {
                            accdv[cur * H3 + j] += dva;
                            if (j < H) accdx[cur * H + j] += dxa;
                        }
                        cur = ld; dva = 0.f; dxa = 0.f;
                    }
                    dva += bf2f(vv[e]) * m2g[u] + m3g[u] * evg[u];
                    if (j < H) dxa += m1g[u];
                }
            }
        }
        if (cur >= 0) {
            accdv[cur * H3 + j] += dva;
            if (j < H) accdx[cur * H + j] += dxa;
        }
        // ---- write next chunk's staging to the other buffer ----
        if (hn) {
            int nb = bsel ^ 1;
            if (j < 128) {
                int e = j >> 3, c8 = j & 7;
                *(short8*)(eeL[nb] + e * EEST + c8 * 8) = ereg;
            }
            if (j < EB) {
                sSrc[nb][j] = msrc; sLd[nb][j] = mdst - n0;
                sEv[nb][j][0] = me0; sEv[nb][j][1] = me1; sEv[nb][j][2] = me2;
            }
        }
        bsel ^= 1;
    }
    __syncthreads();
    // writeout with d1a folded in: x_mid = (x+dx)*c ; vec_mid = vec+dvec
    for (int i = j; i < NPB * H;  i += 384)
        dx_out[(size_t)n0 * H + i] = (xin[(size_t)n0 * H + i] + accdx[i]) * INV_SQRT_2;
    for (int i = j; i < NPB * H3; i += 384)
        dvec_out[(size_t)n0 * H3 + i] = vecin[(size_t)n0 * H3 + i] + accdv[i];
}

// ---------------- D1: vproj MFMA + dot/norm fused (48 rows = 16 nodes) ------
__global__ __launch_bounds__(256) void d1_vproj(const float* __restrict__ vec_mid,
        const short* __restrict__ WvT, float* __restrict__ vec1,
        float* __restrict__ vdot, short* __restrict__ vnorm_bf) {
    __shared__ short A_l[48 * AST];
    __shared__ short B_l[128 * AST];
    __shared__ float T1[48 * 132];
    __shared__ float T2[48 * 132];
    int tid = threadIdx.x;
    int w = tid >> 6, l = tid & 63, lm = l & 15, q = l >> 4;
    int r0 = blockIdx.x * 48;
    const float4* ag = (const float4*)(vec_mid + (size_t)r0 * H);
#pragma unroll
    for (int i = 0; i < 6; ++i) {
        int idx = tid + 256 * i;
        float4 a = ag[idx];
        int row = idx >> 5, c4 = idx & 31;
        short4 s4; s4.x = f2bf(a.x); s4.y = f2bf(a.y); s4.z = f2bf(a.z); s4.w = f2bf(a.w);
        *(short4*)&A_l[row * AST + c4 * 4] = s4;
    }
    for (int s = 0; s < 2; ++s) {
        __syncthreads();
        const short8* wg = (const short8*)(WvT + (size_t)s * 128 * 128);
#pragma unroll
        for (int i = 0; i < 8; ++i) {
            int idx = tid + 256 * i;
            int row = idx >> 4, c8 = idx & 15;
            *(short8*)&B_l[row * AST + c8 * 8] = wg[idx];
        }
        __syncthreads();
        short8 bf[2][4];
#pragma unroll
        for (int c = 0; c < 2; ++c)
#pragma unroll
            for (int ks = 0; ks < 4; ++ks)
                bf[c][ks] = *(const short8*)&B_l[((2 * w + c) * 16 + lm) * AST + ks * 32 + q * 8];
        f32x4 acc[3][2];
#pragma unroll
        for (int rt = 0; rt < 3; ++rt) { acc[rt][0] = (f32x4){0.f,0.f,0.f,0.f}; acc[rt][1] = (f32x4){0.f,0.f,0.f,0.f}; }
#pragma unroll
        for (int ks = 0; ks < 4; ++ks)
#pragma unroll
            for (int rt = 0; rt < 3; ++rt) {
                short8 a = *(const short8*)&A_l[(rt * 16 + lm) * AST + ks * 32 + q * 8];
                acc[rt][0] = __builtin_amdgcn_mfma_f32_16x16x32_bf16(a, bf[0][ks], acc[rt][0], 0, 0, 0);
                acc[rt][1] = __builtin_amdgcn_mfma_f32_16x16x32_bf16(a, bf[1][ks], acc[rt][1], 0, 0, 0);
            }
        float* T = s ? T2 : T1;
#pragma unroll
        for (int c = 0; c < 2; ++c) {
            int col = (2 * w + c) * 16 + lm;
#pragma unroll
            for (int rt = 0; rt < 3; ++rt)
#pragma unroll
                for (int r = 0; r < 4; ++r) {
                    int lr = rt * 16 + q * 4 + r;
                    float v = acc[rt][c][r];
                    T[lr * 132 + col] = v;
                    if (s == 0) vec1[(size_t)(r0 + lr) * H + col] = v;
                }
        }
    }
    __syncthreads();
    int nb = blockIdx.x * 16;
#pragma unroll
    for (int i = 0; i < 8; ++i) {
        int p = tid + 256 * i;  // 2048 (node, col) pairs
        int k = p & 127, m = p >> 7;
        float d = 0.f, s2 = 0.f;
#pragma unroll
        for (int c = 0; c < 3; ++c) {
            float v1 = T1[(m * 3 + c) * 132 + k];
            float v2 = T2[(m * 3 + c) * 132 + k];
            d += v1 * v2; s2 += v2 * v2;
        }
        vdot[(size_t)(nb + m) * H + k] = d * INV_SQRT_H;
        vnorm_bf[(size_t)(nb + m) * H + k] = f2bf(sqrtf(s2 + 1e-8f));
    }
}

// ---------------- D2a: u_bf = bf16(ssilu([x_mid, vnorm] @ Wu1 + bu1)) -------
__global__ __launch_bounds__(256) void d2a_mfma(const float* __restrict__ xmid,
        const short* __restrict__ vnorm_bf, const short* __restrict__ Wu1T,
        const float* __restrict__ bu1, short* __restrict__ u_bf) {
    __shared__ short A_l[64 * AST];
    __shared__ short B_l[128 * AST];
    int tid = threadIdx.x;
    int w = tid >> 6, l = tid & 63, lm = l & 15, q = l >> 4;
    int r0 = blockIdx.x * 64;
    f32x4 acc[4][2];
#pragma unroll
    for (int rt = 0; rt < 4; ++rt) { acc[rt][0] = (f32x4){0.f,0.f,0.f,0.f}; acc[rt][1] = (f32x4){0.f,0.f,0.f,0.f}; }
    for (int kh = 0; kh < 2; ++kh) {
        __syncthreads();
        if (kh == 0) {
            const float4* ag = (const float4*)(xmid + (size_t)r0 * H);
#pragma unroll
            for (int i = 0; i < 8; ++i) {
                int idx = tid + 256 * i;
                float4 a = ag[idx];
                int row = idx >> 5, c4 = idx & 31;
                short4 s4; s4.x = f2bf(a.x); s4.y = f2bf(a.y); s4.z = f2bf(a.z); s4.w = f2bf(a.w);
                *(short4*)&A_l[row * AST + c4 * 4] = s4;
            }
        } else {
            const short8* ag = (const short8*)(vnorm_bf + (size_t)r0 * H);
#pragma unroll
            for (int i = 0; i < 4; ++i) {
                int idx = tid + 256 * i;
                int row = idx >> 4, c8 = idx & 15;
                *(short8*)&A_l[row * AST + c8 * 8] = ag[idx];
            }
        }
#pragma unroll
        for (int i = 0; i < 8; ++i) {
            int idx = tid + 256 * i;
            int row = idx >> 4, c8 = idx & 15;
            *(short8*)&B_l[row * AST + c8 * 8] = ((const short8*)Wu1T)[row * 32 + kh * 16 + c8];
        }
        __syncthreads();
        short8 bf[2][4];
#pragma unroll
        for (int c = 0; c < 2; ++c)
#pragma unroll
            for (int ks = 0; ks < 4; ++ks)
                bf[c][ks] = *(const short8*)&B_l[((2 * w + c) * 16 + lm) * AST + ks * 32 + q * 8];
#pragma unroll
        for (int ks = 0; ks < 4; ++ks)
#pragma unroll
            for (int rt = 0; rt < 4; ++rt) {
                short8 a = *(const short8*)&A_l[(rt * 16 + lm) * AST + ks * 32 + q * 8];
                acc[rt][0] = __builtin_amdgcn_mfma_f32_16x16x32_bf16(a, bf[0][ks], acc[rt][0], 0, 0, 0);
                acc[rt][1] = __builtin_amdgcn_mfma_f32_16x16x32_bf16(a, bf[1][ks], acc[rt][1], 0, 0, 0);
            }
    }
#pragma unroll
    for (int c = 0; c < 2; ++c) {
        int col = (2 * w + c) * 16 + lm;
        float bb = bu1[col];
#pragma unroll
        for (int rt = 0; rt < 4; ++rt)
#pragma unroll
            for (int r = 0; r < 4; ++r) {
                int R = r0 + rt * 16 + q * 4 + r;
                u_bf[(size_t)R * H + col] = f2bf(scaled_silu(acc[rt][c][r] + bb));
            }
    }
}

// ---------------- D2b: h = u @ Wu2 + bu2; final outputs ---------------------
__global__ __launch_bounds__(256) void d2b_mfma(const short* __restrict__ u_bf,
        const short* __restrict__ Wu2T, const float* __restrict__ bu2,
        const float* __restrict__ vdot, const float* __restrict__ xmid,
        const float* __restrict__ vec_mid, const float* __restrict__ vec1,
        float* __restrict__ out) {
    __shared__ short A_l[64 * AST];
    __shared__ short B_l[128 * AST];
    int tid = threadIdx.x;
    int w = tid >> 6, l = tid & 63, lm = l & 15, q = l >> 4;
    int r0 = blockIdx.x * 64;
    float* out_vec = out;
    float* out_x = out + (size_t)NN * H3;
    const short8* ag = (const short8*)(u_bf + (size_t)r0 * H);
#pragma unroll
    for (int i = 0; i < 4; ++i) {
        int idx = tid + 256 * i;
        int row = idx >> 4, c8 = idx & 15;
        *(short8*)&A_l[row * AST + c8 * 8] = ag[idx];
    }
    // stage slice 0, keep frags; stage slice 1, keep frags; dual K-loop
    short8 bf0[2][4], bf1[2][4];
    __syncthreads();
    {
        const short8* wg = (const short8*)Wu2T;
#pragma unroll
        for (int i = 0; i < 8; ++i) {
            int idx = tid + 256 * i;
            int row = idx >> 4, c8 = idx & 15;
            *(short8*)&B_l[row * AST + c8 * 8] = wg[idx];
        }
    }
    __syncthreads();
#pragma unroll
    for (int c = 0; c < 2; ++c)
#pragma unroll
        for (int ks = 0; ks < 4; ++ks)
            bf0[c][ks] = *(const short8*)&B_l[((2 * w + c) * 16 + lm) * AST + ks * 32 + q * 8];
    __syncthreads();
    {
        const short8* wg = (const short8*)(Wu2T + 128 * 128);
#pragma unroll
        for (int i = 0; i < 8; ++i) {
            int idx = tid + 256 * i;
            int row = idx >> 4, c8 = idx & 15;
            *(short8*)&B_l[row * AST + c8 * 8] = wg[idx];
        }
    }
    __syncthreads();
#pragma unroll
    for (int c = 0; c < 2; ++c)
#pragma unroll
        for (int ks = 0; ks < 4; ++ks)
            bf1[c][ks] = *(const short8*)&B_l[((2 * w + c) * 16 + lm) * AST + ks * 32 + q * 8];
    f32x4 acc0[4][2], acc1[4][2];
#pragma unroll
    for (int rt = 0; rt < 4; ++rt) {
        acc0[rt][0] = (f32x4){0.f,0.f,0.f,0.f}; acc0[rt][1] = (f32x4){0.f,0.f,0.f,0.f};
        acc1[rt][0] = (f32x4){0.f,0.f,0.f,0.f}; acc1[rt][1] = (f32x4){0.f,0.f,0.f,0.f};
    }
#pragma unroll
    for (int ks = 0; ks < 4; ++ks)
#pragma unroll
        for (int rt = 0; rt < 4; ++rt) {
            short8 a = *(const short8*)&A_l[(rt * 16 + lm) * AST + ks * 32 + q * 8];
            acc0[rt][0] = __builtin_amdgcn_mfma_f32_16x16x32_bf16(a, bf0[0][ks], acc0[rt][0], 0, 0, 0);
            acc0[rt][1] = __builtin_amdgcn_mfma_f32_16x16x32_bf16(a, bf0[1][ks], acc0[rt][1], 0, 0, 0);
            acc1[rt][0] = __builtin_amdgcn_mfma_f32_16x16x32_bf16(a, bf1[0][ks], acc1[rt][0], 0, 0, 0);
            acc1[rt][1] = __builtin_amdgcn_mfma_f32_16x16x32_bf16(a, bf1[1][ks], acc1[rt][1], 0, 0, 0);
        }
    // epilogue: out_x = x_mid + (xv1 + xv2*vdot)*INV_SQRT_2
#pragma unroll
    for (int c = 0; c < 2; ++c) {
        int col = (2 * w + c) * 16 + lm;
        float bb0 = bu2[col], bb1 = bu2[H + col];
#pragma unroll
        for (int rt = 0; rt < 4; ++rt)
#pragma unroll
            for (int r = 0; r < 4; ++r) {
                int R = r0 + rt * 16 + q * 4 + r;
                float xv1 = acc0[rt][c][r] + bb0;
                float xv2 = acc1[rt][c][r] + bb1;
                float dx2 = (xv1 + xv2 * vdot[(size_t)R * H + col]) * INV_SQRT_2;
                out_x[(size_t)R * H + col] = xmid[(size_t)R * H + col] + dx2;
            }
    }
    // slice 2 (xv3) -> out_vec
    __syncthreads();
    {
        const short8* wg = (const short8*)(Wu2T + 2 * 128 * 128);
#pragma unroll
        for (int i = 0; i < 8; ++i) {
            int idx = tid + 256 * i;
            int row = idx >> 4, c8 = idx & 15;
            *(short8*)&B_l[row * AST + c8 * 8] = wg[idx];
        }
    }
    __syncthreads();
#pragma unroll
    for (int c = 0; c < 2; ++c)
#pragma unroll
        for (int ks = 0; ks < 4; ++ks)
            bf0[c][ks] = *(const short8*)&B_l[((2 * w + c) * 16 + lm) * AST + ks * 32 + q * 8];
#pragma unroll
    for (int rt = 0; rt < 4; ++rt) { acc0[rt][0] = (f32x4){0.f,0.f,0.f,0.f}; acc0[rt][1] = (f32x4){0.f,0.f,0.f,0.f}; }
#pragma unroll
    for (int ks = 0; ks < 4; ++ks)
#pragma unroll
        for (int rt = 0; rt < 4; ++rt) {
            short8 a = *(const short8*)&A_l[(rt * 16 + lm) * AST + ks * 32 + q * 8];
            acc0[rt][0] = __builtin_amdgcn_mfma_f32_16x16x32_bf16(a, bf0[0][ks], acc0[rt][0], 0, 0, 0);
            acc0[rt][1] = __builtin_amdgcn_mfma_f32_16x16x32_bf16(a, bf0[1][ks], acc0[rt][1], 0, 0, 0);
        }
#pragma unroll
    for (int c = 0; c < 2; ++c) {
        int col = (2 * w + c) * 16 + lm;
        float bb2 = bu2[2 * H + col];
#pragma unroll
        for (int rt = 0; rt < 4; ++rt)
#pragma unroll
            for (int r = 0; r < 4; ++r) {
                int R = r0 + rt * 16 + q * 4 + r;
                float xv3 = acc0[rt][c][r] + bb2;
#pragma unroll
                for (int c3 = 0; c3 < 3; ++c3) {
                    size_t idx = (size_t)R * H3 + c3 * H + col;
                    out_vec[idx] = vec_mid[idx] + xv3 * vec1[idx];
                }
            }
    }
}

extern "C" void kernel_launch(void* const* d_in, const int* in_sizes, int n_in,
                              void* d_out, int out_size, void* d_ws, size_t ws_size,
                              hipStream_t stream) {
    const float* x    = (const float*)d_in[0];
    const float* vec  = (const float*)d_in[1];
    const int*   eidx = (const int*)d_in[2];
    const float* eemb = (const float*)d_in[3];
    const float* evec = (const float*)d_in[4];
    const float* lng  = (const float*)d_in[5];
    const float* lnb  = (const float*)d_in[6];
    const float* W1   = (const float*)d_in[7];
    const float* b1   = (const float*)d_in[8];
    const float* W2   = (const float*)d_in[9];
    const float* b2   = (const float*)d_in[10];
    const float* Wr   = (const float*)d_in[11];
    const float* br   = (const float*)d_in[12];
    const float* Wv   = (const float*)d_in[13];
    const float* Wu1  = (const float*)d_in[14];
    const float* bu1  = (const float*)d_in[15];
    const float* Wu2  = (const float*)d_in[16];
    const float* bu2  = (const float*)d_in[17];

    // workspace layout:
    // B0: N*384 f32 : xh_bf16 (as shorts) -> vec1 f32
    // B1: N*384 f32 : vec_mid (edge kernel writes directly)
    // B2: N*128 f32 : t(LN) -> x_mid (edge kernel writes directly)
    // B3: N*128 f32 : h1_bf16 (as shorts) -> vec_dot f32
    // B4: N*128 f32 : [sort scratch + WrT16] -> vnorm_bf16 + u_bf16
    // B5: vec_bf16 (N*384 shorts) + bf16 transposed weights
    // ee_sorted (NE*64 bf16 = 67MB) lives in d_out (overwritten by d2b later)
    float* B0 = (float*)d_ws;
    float* B1 = B0 + (size_t)NN * H3;
    float* B2 = B1 + (size_t)NN * H3;
    float* B3 = B2 + (size_t)NN * H;
    float* B4 = B3 + (size_t)NN * H;
    short* B5 = (short*)(B4 + (size_t)NN * H);
    float* out = (float*)d_out;
    short* ee_s = (short*)d_out;   // NE*64 shorts == out_size bytes exactly

    int* row_ptr = (int*)B4;
    int* cursor  = row_ptr + 32772;
    int* perm    = cursor + 32768;
    int* srcs_s  = perm + NE;
    int* dsts_s  = srcs_s + NE;
    float* ev_s  = (float*)(dsts_s + NE);
    short* WrT16 = (short*)(ev_s + (size_t)NE * 3);

    short* vec_bf = B5;
    short* W1T  = vec_bf + (size_t)NN * H3;
    short* W2T  = W1T + 128 * 128;
    short* WvT  = W2T + 128 * 384;
    short* Wu1T = WvT + 128 * 256;
    short* Wu2T = Wu1T + 256 * 128;

    short* xh_bf    = (short*)B0;
    short* h1_bf    = (short*)B3;
    short* vnorm_bf = (short*)B4;
    short* u_bf     = vnorm_bf + (size_t)NN * H;

    // weight conversions + vec bf16 copy
    cvtT_kernel<<<64,  256, 0, stream>>>(W1,  W1T,  128, 128);
    cvtT_kernel<<<192, 256, 0, stream>>>(W2,  W2T,  128, 384);
    cvtT_kernel<<<128, 256, 0, stream>>>(Wv,  WvT,  128, 256);
    cvtT_kernel<<<128, 256, 0, stream>>>(Wu1, Wu1T, 256, 128);
    cvtT_kernel<<<192, 256, 0, stream>>>(Wu2, Wu2T, 128, 384);
    wrt_kernel<<<(H3 * RB) / 256, 256, 0, stream>>>(Wr, WrT16);
    veccvt_kernel<<<(NN * H3 / 4) / 256, 256, 0, stream>>>(vec, vec_bf);

    // node message path
    ln_kernel<<<NN / 4, 256, 0, stream>>>(x, lng, lnb, B2);
    g1_mfma<<<NN / 64, 256, 0, stream>>>(B2, W1T, b1, h1_bf);
    g2_mfma<<<NN / 64, 256, 0, stream>>>(h1_bf, W2T, b2, xh_bf);

    // dst counting sort -> CSR, then pre-gather eembed into sorted bf16 rows
    hipMemsetAsync(row_ptr, 0, 32768 * sizeof(int), stream);
    hist_kernel<<<NE / 256, 256, 0, stream>>>(eidx, row_ptr);
    scan_kernel<<<1, 1024, 0, stream>>>(row_ptr, row_ptr, cursor);
    scatter_kernel<<<NE / 256, 256, 0, stream>>>(eidx, evec, cursor, perm, srcs_s, dsts_s, ev_s);
    eegather_kernel<<<(NE * 8) / 256, 256, 0, stream>>>(perm, eemb, ee_s);

    // fused edge message + segment reduce + d1a fold
    // (x_mid -> B2, vec_mid -> B1)
    edge_mfma_kernel<<<NN / NPB, 384, 0, stream>>>(row_ptr, srcs_s, dsts_s, ev_s,
                                                   ee_s, WrT16, br, xh_bf, vec_bf,
                                                   x, vec, B2, B1);

    // update path
    d1_vproj<<<(NN * 3) / 48, 256, 0, stream>>>(B1, WvT, B0, B3, vnorm_bf);
    d2a_mfma<<<NN / 64, 256, 0, stream>>>(B2, vnorm_bf, Wu1T, bu1, u_bf);
    d2b_mfma<<<NN / 64, 256, 0, stream>>>(u_bf, Wu2T, bu2, B3, B2, B1, B0, out);
}